// Round 7
// baseline (937.848 us; speedup 1.0000x reference)
//
#include <hip/hip_runtime.h>

#define N_NODES 100000
#define D_IN 64
#define HID 128
#define N_EDGES 1600000
#define N_LBL 500000

// ---- bf16 helpers (RNE) ----
__device__ inline unsigned short f2bf(float f) {
  unsigned int u = __float_as_uint(f);
  return (unsigned short)((u + 0x7FFFu + ((u >> 16) & 1u)) >> 16);
}
__device__ inline float bf2f(unsigned short s) {
  return __uint_as_float(((unsigned int)s) << 16);
}

// ---------------- degree histogram (int) ----------------
__global__ __launch_bounds__(256) void k_deg(const int* __restrict__ dst,
                                             int* __restrict__ deg) {
  int e = blockIdx.x * 256 + threadIdx.x;
  if (e < N_EDGES) atomicAdd(&deg[dst[e]], 1);
}

// ---------------- exclusive scan over degrees + inv (single block, wave-shfl) ----
// NOTE: cursor may alias deg (reads of deg[i] happen before cursor[i] write,
// chunks processed in increasing i) -> no __restrict__ on deg/cursor.
__global__ __launch_bounds__(1024) void k_scan(const int* deg,
                                               int* __restrict__ rowptr,
                                               int* cursor,
                                               float* __restrict__ inv) {
  __shared__ int s_wsum[16];
  __shared__ int s_carry;
  const int lane = threadIdx.x & 63;
  const int wid = threadIdx.x >> 6;
  if (threadIdx.x == 0) s_carry = 0;
  __syncthreads();
  for (int base = 0; base < N_NODES; base += 1024) {
    int i = base + threadIdx.x;
    int v = (i < N_NODES) ? deg[i] : 0;
    int x = v;  // inclusive wave scan
#pragma unroll
    for (int off = 1; off < 64; off <<= 1) {
      int t = __shfl_up(x, off);
      if (lane >= off) x += t;
    }
    if (lane == 63) s_wsum[wid] = x;
    __syncthreads();
    if (wid == 0 && lane < 16) {
      int ws = s_wsum[lane];
      int y = ws;
#pragma unroll
      for (int off = 1; off < 16; off <<= 1) {
        int t = __shfl_up(y, off);
        if (lane >= off) y += t;
      }
      s_wsum[lane] = y - ws;  // exclusive wave offsets
    }
    __syncthreads();
    int t = s_carry + s_wsum[wid] + (x - v);
    if (i < N_NODES) {
      rowptr[i] = t;
      cursor[i] = t;
      inv[i] = v > 0 ? 1.0f / (float)v : 0.0f;
    }
    __syncthreads();
    if (threadIdx.x == 1023) s_carry = t + v;
    __syncthreads();
  }
  if (threadIdx.x == 0) rowptr[N_NODES] = s_carry;
}

// ---------------- CSR fill ----------------
__global__ __launch_bounds__(256) void k_fill(const int* __restrict__ src,
                                              const int* __restrict__ dst,
                                              int* cursor,
                                              int* __restrict__ csr) {
  int e = blockIdx.x * 256 + threadIdx.x;
  if (e < N_EDGES) {
    int pos = atomicAdd(&cursor[dst[e]], 1);
    csr[pos] = src[e];
  }
}

// ---------------- gather aggregation (fp32 feat, D=64): wave per node ----------------
__global__ __launch_bounds__(256) void k_agg64(const int* __restrict__ rowptr,
                                               const int* __restrict__ csr,
                                               const float* __restrict__ feat,
                                               const float* __restrict__ inv,
                                               float* __restrict__ out) {
  const int lane = threadIdx.x & 63;
  const int n = blockIdx.x * 4 + (threadIdx.x >> 6);  // grid exact: 25000*4
  const int beg = rowptr[n], end = rowptr[n + 1];
  float acc = 0.0f;
  int j = beg;
  for (; j + 4 <= end; j += 4) {
    int s0 = csr[j], s1 = csr[j + 1], s2 = csr[j + 2], s3 = csr[j + 3];
    float f0 = feat[(long)s0 * 64 + lane];
    float f1 = feat[(long)s1 * 64 + lane];
    float f2 = feat[(long)s2 * 64 + lane];
    float f3 = feat[(long)s3 * 64 + lane];
    acc += f0; acc += f1; acc += f2; acc += f3;
  }
  for (; j < end; ++j) acc += feat[(long)csr[j] * 64 + lane];
  out[(long)n * 64 + lane] = acc * inv[n];
}

// ---------------- gather aggregation (bf16 feat, D=128): wave per node ----------------
__global__ __launch_bounds__(256) void k_agg128(const int* __restrict__ rowptr,
                                                const int* __restrict__ csr,
                                                const unsigned short* __restrict__ feat16,
                                                const float* __restrict__ inv,
                                                float* __restrict__ out) {
  const int lane = threadIdx.x & 63;
  const int n = blockIdx.x * 4 + (threadIdx.x >> 6);  // grid exact: 25000*4
  const int beg = rowptr[n], end = rowptr[n + 1];
  float ax = 0.0f, ay = 0.0f;
  int j = beg;
  for (; j + 4 <= end; j += 4) {
    int s0 = csr[j], s1 = csr[j + 1], s2 = csr[j + 2], s3 = csr[j + 3];
    unsigned int w0 = *(const unsigned int*)&feat16[(long)s0 * 128 + lane * 2];
    unsigned int w1 = *(const unsigned int*)&feat16[(long)s1 * 128 + lane * 2];
    unsigned int w2 = *(const unsigned int*)&feat16[(long)s2 * 128 + lane * 2];
    unsigned int w3 = *(const unsigned int*)&feat16[(long)s3 * 128 + lane * 2];
    ax += __uint_as_float(w0 << 16); ay += __uint_as_float(w0 & 0xFFFF0000u);
    ax += __uint_as_float(w1 << 16); ay += __uint_as_float(w1 & 0xFFFF0000u);
    ax += __uint_as_float(w2 << 16); ay += __uint_as_float(w2 & 0xFFFF0000u);
    ax += __uint_as_float(w3 << 16); ay += __uint_as_float(w3 & 0xFFFF0000u);
  }
  for (; j < end; ++j) {
    unsigned int w = *(const unsigned int*)&feat16[(long)csr[j] * 128 + lane * 2];
    ax += __uint_as_float(w << 16); ay += __uint_as_float(w & 0xFFFF0000u);
  }
  float iv = inv[n];
  float2 o = {ax * iv, ay * iv};
  *(float2*)&out[(long)n * 128 + lane * 2] = o;
}

// ---------------- register-tiled fused SAGE layer (no input LDS) ----------------
// Block: 256 thr, tile 64 rows x 128 cols, 8 rows x 4 cols per thread.
// mean/xin read directly from global: within a wave, rows are shared by 32
// threads (broadcast) -> L1-served; weights coalesced from L2.
// out = act(mean@wl + bl + xin@wr); if BF16OUT also writes bf16 copy.
// If DO_UV: z = result (through LDS), u = z@dw1[0:128] -> out, v -> vout.
// Aliasing (fused call): out==mean, vout==xin; all input reads precede the
// z-stash __syncthreads(), all global writes follow it; blocks row-disjoint.
// (mean/xin/out/vout deliberately NOT __restrict__.)
template <int K, bool RELU, bool DO_UV, bool BF16OUT>
__global__ __launch_bounds__(256) void k_layer(
    const float* mean, const float* xin,
    const float* __restrict__ wl, const float* __restrict__ bl,
    const float* __restrict__ wr, const float* __restrict__ dw1,
    float* out, float* vout, unsigned short* __restrict__ out16) {
  __shared__ float s_z[DO_UV ? 64 : 1][DO_UV ? HID : 4];
  const int tx = threadIdx.x & 31;  // 32 col groups of 4
  const int ty = threadIdx.x >> 5;  // 8 row groups of 8
  const int row0 = blockIdx.x * 64; // grid: 1563 (tail guarded)
  const int c0 = tx * 4;
  const int r0 = ty * 8;

  int roff[8];
  bool valid[8];
#pragma unroll
  for (int j = 0; j < 8; ++j) {
    int row = row0 + r0 + j;
    valid[j] = row < N_NODES;
    roff[j] = (valid[j] ? row : 0) * K;
  }

  float acc[8][4];
  {
    float4 bv = *(const float4*)&bl[c0];
#pragma unroll
    for (int j = 0; j < 8; ++j) {
      acc[j][0] = bv.x; acc[j][1] = bv.y; acc[j][2] = bv.z; acc[j][3] = bv.w;
    }
  }

  for (int kk = 0; kk < K; kk += 4) {
    float W1[4][4], W2[4][4];
#pragma unroll
    for (int t = 0; t < 4; ++t) {
      float4 a = *(const float4*)&wl[(long)(kk + t) * HID + c0];
      float4 b = *(const float4*)&wr[(long)(kk + t) * HID + c0];
      W1[t][0] = a.x; W1[t][1] = a.y; W1[t][2] = a.z; W1[t][3] = a.w;
      W2[t][0] = b.x; W2[t][1] = b.y; W2[t][2] = b.z; W2[t][3] = b.w;
    }
#pragma unroll
    for (int jc = 0; jc < 2; ++jc) {
      float A[4][4], X[4][4];
#pragma unroll
      for (int j = 0; j < 4; ++j) {
        float4 av = *(const float4*)&mean[roff[jc * 4 + j] + kk];
        float4 xv = *(const float4*)&xin[roff[jc * 4 + j] + kk];
        A[j][0] = av.x; A[j][1] = av.y; A[j][2] = av.z; A[j][3] = av.w;
        X[j][0] = xv.x; X[j][1] = xv.y; X[j][2] = xv.z; X[j][3] = xv.w;
      }
#pragma unroll
      for (int t = 0; t < 4; ++t)
#pragma unroll
        for (int j = 0; j < 4; ++j)
#pragma unroll
          for (int i = 0; i < 4; ++i)
            acc[jc * 4 + j][i] =
                fmaf(A[j][t], W1[t][i], fmaf(X[j][t], W2[t][i], acc[jc * 4 + j][i]));
    }
  }

  if (!DO_UV) {
#pragma unroll
    for (int j = 0; j < 8; ++j) {
      if (valid[j]) {
        long o = (long)(row0 + r0 + j) * HID + c0;
        float4 ov;
        ov.x = RELU ? fmaxf(acc[j][0], 0.0f) : acc[j][0];
        ov.y = RELU ? fmaxf(acc[j][1], 0.0f) : acc[j][1];
        ov.z = RELU ? fmaxf(acc[j][2], 0.0f) : acc[j][2];
        ov.w = RELU ? fmaxf(acc[j][3], 0.0f) : acc[j][3];
        *(float4*)&out[o] = ov;
        if (BF16OUT) {
          ushort4 q = {f2bf(ov.x), f2bf(ov.y), f2bf(ov.z), f2bf(ov.w)};
          *(ushort4*)&out16[o] = q;
        }
      }
    }
  } else {
    // stash z into LDS (row-major; writes dense, reads broadcast)
#pragma unroll
    for (int j = 0; j < 8; ++j) {
      float4 o = {acc[j][0], acc[j][1], acc[j][2], acc[j][3]};
      *(float4*)&s_z[r0 + j][c0] = o;
    }
    __syncthreads();

    float u[8][4], v[8][4];
#pragma unroll
    for (int j = 0; j < 8; ++j)
#pragma unroll
      for (int i = 0; i < 4; ++i) { u[j][i] = 0.0f; v[j][i] = 0.0f; }

    for (int kk = 0; kk < HID; kk += 4) {
      float W1[4][4], W2[4][4];
#pragma unroll
      for (int t = 0; t < 4; ++t) {
        float4 a = *(const float4*)&dw1[(long)(kk + t) * HID + c0];
        float4 b = *(const float4*)&dw1[(long)(kk + t + HID) * HID + c0];
        W1[t][0] = a.x; W1[t][1] = a.y; W1[t][2] = a.z; W1[t][3] = a.w;
        W2[t][0] = b.x; W2[t][1] = b.y; W2[t][2] = b.z; W2[t][3] = b.w;
      }
#pragma unroll
      for (int jc = 0; jc < 2; ++jc) {
        float Z[4][4];
#pragma unroll
        for (int j = 0; j < 4; ++j) {
          float4 zv = *(const float4*)&s_z[r0 + jc * 4 + j][kk];
          Z[j][0] = zv.x; Z[j][1] = zv.y; Z[j][2] = zv.z; Z[j][3] = zv.w;
        }
#pragma unroll
        for (int t = 0; t < 4; ++t)
#pragma unroll
          for (int j = 0; j < 4; ++j)
#pragma unroll
            for (int i = 0; i < 4; ++i) {
              u[jc * 4 + j][i] = fmaf(Z[j][t], W1[t][i], u[jc * 4 + j][i]);
              v[jc * 4 + j][i] = fmaf(Z[j][t], W2[t][i], v[jc * 4 + j][i]);
            }
      }
    }

#pragma unroll
    for (int j = 0; j < 8; ++j) {
      if (valid[j]) {
        long o = (long)(row0 + r0 + j) * HID + c0;
        float4 ou = {u[j][0], u[j][1], u[j][2], u[j][3]};
        float4 ov = {v[j][0], v[j][1], v[j][2], v[j][3]};
        *(float4*)&out[o] = ou;
        *(float4*)&vout[o] = ov;
      }
    }
  }
}

// ---------------- per-label-edge decoder ----------------
__global__ __launch_bounds__(256) void k_edge(const int* __restrict__ ls,
                                              const int* __restrict__ ld,
                                              const float* __restrict__ u,
                                              const float* __restrict__ v,
                                              const float* __restrict__ db1,
                                              const float* __restrict__ dw2,
                                              const float* __restrict__ db2,
                                              float* __restrict__ out) {
  int lane = threadIdx.x & 63;
  long e = (long)blockIdx.x * 4 + (threadIdx.x >> 6);  // grid exact: 125000*4
  int s = ls[e], d = ld[e];
  const float2 uu = *(const float2*)&u[(long)s * HID + lane * 2];
  const float2 vv = *(const float2*)&v[(long)d * HID + lane * 2];
  const float2 b = *(const float2*)&db1[lane * 2];
  const float2 w = *(const float2*)&dw2[lane * 2];
  float h0 = fmaxf(uu.x + vv.x + b.x, 0.0f);
  float h1 = fmaxf(uu.y + vv.y + b.y, 0.0f);
  float sum = h0 * w.x + h1 * w.y;
#pragma unroll
  for (int o = 32; o > 0; o >>= 1) sum += __shfl_down(sum, o);
  if (lane == 0) out[e] = sum + db2[0];
}

extern "C" void kernel_launch(void* const* d_in, const int* in_sizes, int n_in,
                              void* d_out, int out_size, void* d_ws, size_t ws_size,
                              hipStream_t stream) {
  const float* x   = (const float*)d_in[0];
  const int*   ei  = (const int*)d_in[1];
  const int*   eli = (const int*)d_in[2];
  const float* w1l = (const float*)d_in[3];
  const float* b1l = (const float*)d_in[4];
  const float* w1r = (const float*)d_in[5];
  const float* w2l = (const float*)d_in[6];
  const float* b2l = (const float*)d_in[7];
  const float* w2r = (const float*)d_in[8];
  const float* dw1 = (const float*)d_in[9];
  const float* db1 = (const float*)d_in[10];
  const float* dw2 = (const float*)d_in[11];
  const float* db2 = (const float*)d_in[12];
  float* out = (float*)d_out;

  // ---- workspace layout (bytes) ----
  //   inv    [0,          400000)   100000 f
  //   deg_i  [400000,     800000)   100000 i  (reused as cursor after scan)
  //   rowptr [800000,    1200032)   100008 i
  //   csr    [1200032,   7600032)   1.6M i
  //   h16    [7600032,  33200032)   12.8M ushort (bf16 h)
  //   cbuf   [33200032, 84400032)   12.8M f (mean1/mean2 -> u)
  //   hbuf   [84400032,135600032)   12.8M f (h fp32 -> v)
  float* ws     = (float*)d_ws;
  float* inv    = ws;
  int*   deg_i  = (int*)(ws + 100000);
  int*   rowptr = deg_i + 100000;
  int*   csr    = rowptr + 100008;
  unsigned short* h16 = (unsigned short*)(csr + 1600000);
  float* cbuf   = (float*)(h16 + 12800000);
  float* hbuf   = cbuf + (size_t)N_NODES * HID;

  const int* srcp = ei;
  const int* dstp = ei + N_EDGES;
  const int* lsp  = eli;
  const int* ldp  = eli + N_LBL;

  // ---- CSR build ----
  hipMemsetAsync(deg_i, 0, N_NODES * sizeof(int), stream);
  k_deg<<<N_EDGES / 256, 256, 0, stream>>>(dstp, deg_i);
  k_scan<<<1, 1024, 0, stream>>>(deg_i, rowptr, deg_i /*cursor*/, inv);
  k_fill<<<N_EDGES / 256, 256, 0, stream>>>(srcp, dstp, deg_i /*cursor*/, csr);

  // ---- layer 1: mean1 -> cbuf (N x 64); h -> hbuf (fp32) + h16 (bf16) ----
  k_agg64<<<N_NODES / 4, 256, 0, stream>>>(rowptr, csr, x, inv, cbuf);
  k_layer<64, true, false, true><<<(N_NODES + 63) / 64, 256, 0, stream>>>(
      cbuf, x, w1l, b1l, w1r, nullptr, hbuf, nullptr, h16);

  // ---- layer 2 + decoder-precompute fused:
  //      mean2 (gather bf16 h) -> cbuf; z in LDS; u -> cbuf, v -> hbuf ----
  k_agg128<<<N_NODES / 4, 256, 0, stream>>>(rowptr, csr, h16, inv, cbuf);
  k_layer<128, false, true, false><<<(N_NODES + 63) / 64, 256, 0, stream>>>(
      cbuf, hbuf, w2l, b2l, w2r, dw1, cbuf, hbuf, nullptr);

  // ---- decoder edge MLP ----
  k_edge<<<N_LBL / 4, 256, 0, stream>>>(lsp, ldp, cbuf, hbuf, db1, dw2, db2, out);
}

// Round 9
// 717.849 us; speedup vs baseline: 1.3065x; 1.3065x over previous
//
#include <hip/hip_runtime.h>

#define N_NODES 100000
#define D_IN 64
#define HID 128
#define N_EDGES 1600000
#define N_LBL 500000

typedef __attribute__((ext_vector_type(8))) short bf16x8;
typedef __attribute__((ext_vector_type(4))) float f32x4;

// ---- bf16 helpers (RNE) ----
__device__ inline unsigned short f2bf(float f) {
  unsigned int u = __float_as_uint(f);
  return (unsigned short)((u + 0x7FFFu + ((u >> 16) & 1u)) >> 16);
}
__device__ inline float bf_lo(unsigned int w) { return __uint_as_float(w << 16); }
__device__ inline float bf_hi(unsigned int w) { return __uint_as_float(w & 0xFFFF0000u); }

// ---------------- degree histogram (int) ----------------
__global__ __launch_bounds__(256) void k_deg(const int* __restrict__ dst,
                                             int* __restrict__ deg) {
  int e = blockIdx.x * 256 + threadIdx.x;
  if (e < N_EDGES) atomicAdd(&deg[dst[e]], 1);
}

// ---------------- scan + inv (single block). cursor aliases deg. ----------------
__global__ __launch_bounds__(1024) void k_scan(const int* deg,
                                               int* __restrict__ rowptr,
                                               int* cursor,
                                               float* __restrict__ inv) {
  __shared__ int s_wsum[16];
  __shared__ int s_carry;
  const int lane = threadIdx.x & 63;
  const int wid = threadIdx.x >> 6;
  if (threadIdx.x == 0) s_carry = 0;
  __syncthreads();
  for (int base = 0; base < N_NODES; base += 1024) {
    int i = base + threadIdx.x;
    int v = (i < N_NODES) ? deg[i] : 0;
    int x = v;
#pragma unroll
    for (int off = 1; off < 64; off <<= 1) {
      int t = __shfl_up(x, off);
      if (lane >= off) x += t;
    }
    if (lane == 63) s_wsum[wid] = x;
    __syncthreads();
    if (wid == 0 && lane < 16) {
      int ws = s_wsum[lane];
      int y = ws;
#pragma unroll
      for (int off = 1; off < 16; off <<= 1) {
        int t = __shfl_up(y, off);
        if (lane >= off) y += t;
      }
      s_wsum[lane] = y - ws;
    }
    __syncthreads();
    int t = s_carry + s_wsum[wid] + (x - v);
    if (i < N_NODES) {
      rowptr[i] = t;
      cursor[i] = t;
      inv[i] = v > 0 ? 1.0f / (float)v : 0.0f;
    }
    __syncthreads();
    if (threadIdx.x == 1023) s_carry = t + v;
    __syncthreads();
  }
  if (threadIdx.x == 0) rowptr[N_NODES] = s_carry;
}

// ---------------- CSR fill ----------------
__global__ __launch_bounds__(256) void k_fill(const int* __restrict__ src,
                                              const int* __restrict__ dst,
                                              int* cursor,
                                              int* __restrict__ csr) {
  int e = blockIdx.x * 256 + threadIdx.x;
  if (e < N_EDGES) {
    int pos = atomicAdd(&cursor[dst[e]], 1);
    csr[pos] = src[e];
  }
}

// ---------------- weight prep: w2l,w2r,dw1 -> bf16 transposed [n][k] ----------------
// 65536 threads exact (256 blocks).
__global__ __launch_bounds__(256) void k_prep_w(
    const float* __restrict__ w2l, const float* __restrict__ w2r,
    const float* __restrict__ dw1,
    unsigned short* __restrict__ w2lt, unsigned short* __restrict__ w2rt,
    unsigned short* __restrict__ dw1t) {
  int idx = blockIdx.x * 256 + threadIdx.x;
  if (idx < 16384) {
    int n = idx >> 7, k = idx & 127;
    w2lt[idx] = f2bf(w2l[k * 128 + n]);
    return;
  }
  idx -= 16384;
  if (idx < 16384) {
    int n = idx >> 7, k = idx & 127;
    w2rt[idx] = f2bf(w2r[k * 128 + n]);
    return;
  }
  idx -= 16384;
  {
    int n = idx >> 7, k = idx & 127;
    dw1t[idx] = f2bf(n < 128 ? dw1[k * 128 + n] : dw1[(k + 128) * 128 + (n - 128)]);
  }
}

// ---------------- gather aggregation D=64 (fp32 in/out): wave per node ----------------
__global__ __launch_bounds__(256) void k_agg64(const int* __restrict__ rowptr,
                                               const int* __restrict__ csr,
                                               const float* __restrict__ feat,
                                               const float* __restrict__ inv,
                                               float* __restrict__ out) {
  const int lane = threadIdx.x & 63;
  const int n = blockIdx.x * 4 + (threadIdx.x >> 6);  // grid exact: 25000*4
  const int beg = rowptr[n], end = rowptr[n + 1];
  float acc = 0.0f;
  int j = beg;
  for (; j + 4 <= end; j += 4) {
    int s0 = csr[j], s1 = csr[j + 1], s2 = csr[j + 2], s3 = csr[j + 3];
    float f0 = feat[(long)s0 * 64 + lane];
    float f1 = feat[(long)s1 * 64 + lane];
    float f2 = feat[(long)s2 * 64 + lane];
    float f3 = feat[(long)s3 * 64 + lane];
    acc += f0; acc += f1; acc += f2; acc += f3;
  }
  for (; j < end; ++j) acc += feat[(long)csr[j] * 64 + lane];
  out[(long)n * 64 + lane] = acc * inv[n];
}

// ---------------- layer 1 (fp32 vector math, round-6 structure): ----------------
// h16 = bf16(relu(mean1@w1l + b1l + x@w1r)); mean staged in LDS, x from global.
__global__ __launch_bounds__(256) void k_l1(
    const float* __restrict__ mean, const float* __restrict__ xin,
    const float* __restrict__ wl, const float* __restrict__ bl,
    const float* __restrict__ wr, unsigned short* __restrict__ h16) {
  __shared__ float s_a[64][64];     // 16 KB
  const int tx = threadIdx.x & 31;  // 32 col groups of 4
  const int ty = threadIdx.x >> 5;  // 8 row groups of 8
  const int row0 = blockIdx.x * 64; // grid 1563, tail guarded
  const int c0 = tx * 4;
  const int r0 = ty * 8;

  for (int t = threadIdx.x; t < 64 * 16; t += 256) {
    int r = t >> 4, kg = t & 15;
    long row = row0 + r;
    float4 v = {0.0f, 0.0f, 0.0f, 0.0f};
    if (row < N_NODES) v = *(const float4*)&mean[row * 64 + kg * 4];
    *(float4*)&s_a[r][kg * 4] = v;
  }
  int xoff[8];
  bool valid[8];
#pragma unroll
  for (int j = 0; j < 8; ++j) {
    int row = row0 + r0 + j;
    valid[j] = row < N_NODES;
    xoff[j] = (valid[j] ? row : 0) * 64;
  }
  __syncthreads();

  float acc[8][4];
  {
    float4 bv = *(const float4*)&bl[c0];
#pragma unroll
    for (int j = 0; j < 8; ++j) {
      acc[j][0] = bv.x; acc[j][1] = bv.y; acc[j][2] = bv.z; acc[j][3] = bv.w;
    }
  }

  for (int kk = 0; kk < 64; kk += 4) {
    float A[8][4], X[8][4];
#pragma unroll
    for (int j = 0; j < 8; ++j) {
      float4 av = *(const float4*)&s_a[r0 + j][kk];
      A[j][0] = av.x; A[j][1] = av.y; A[j][2] = av.z; A[j][3] = av.w;
    }
#pragma unroll
    for (int j = 0; j < 8; ++j) {
      float4 xv = *(const float4*)&xin[xoff[j] + kk];
      X[j][0] = xv.x; X[j][1] = xv.y; X[j][2] = xv.z; X[j][3] = xv.w;
    }
#pragma unroll
    for (int t = 0; t < 4; ++t) {
      float4 wlv = *(const float4*)&wl[(long)(kk + t) * HID + c0];
      float4 wrv = *(const float4*)&wr[(long)(kk + t) * HID + c0];
      float WL[4] = {wlv.x, wlv.y, wlv.z, wlv.w};
      float WR[4] = {wrv.x, wrv.y, wrv.z, wrv.w};
#pragma unroll
      for (int j = 0; j < 8; ++j)
#pragma unroll
        for (int i = 0; i < 4; ++i)
          acc[j][i] = fmaf(A[j][t], WL[i], fmaf(X[j][t], WR[i], acc[j][i]));
    }
  }

#pragma unroll
  for (int j = 0; j < 8; ++j) {
    if (valid[j]) {
      long o = (long)(row0 + r0 + j) * HID + c0;
      ushort4 q = {f2bf(fmaxf(acc[j][0], 0.0f)), f2bf(fmaxf(acc[j][1], 0.0f)),
                   f2bf(fmaxf(acc[j][2], 0.0f)), f2bf(fmaxf(acc[j][3], 0.0f))};
      *(ushort4*)&h16[o] = q;
    }
  }
}

// ---------------- gather aggregation D=128 (bf16 in, bf16 out) ----------------
__global__ __launch_bounds__(256) void k_agg128(const int* __restrict__ rowptr,
                                                const int* __restrict__ csr,
                                                const unsigned short* __restrict__ f16,
                                                const float* __restrict__ inv,
                                                unsigned short* __restrict__ out16) {
  const int lane = threadIdx.x & 63;
  const int n = blockIdx.x * 4 + (threadIdx.x >> 6);  // grid exact: 25000*4
  const int beg = rowptr[n], end = rowptr[n + 1];
  float ax = 0.0f, ay = 0.0f;
  int j = beg;
  for (; j + 4 <= end; j += 4) {
    int s0 = csr[j], s1 = csr[j + 1], s2 = csr[j + 2], s3 = csr[j + 3];
    unsigned int w0 = *(const unsigned int*)&f16[(long)s0 * 128 + lane * 2];
    unsigned int w1 = *(const unsigned int*)&f16[(long)s1 * 128 + lane * 2];
    unsigned int w2 = *(const unsigned int*)&f16[(long)s2 * 128 + lane * 2];
    unsigned int w3 = *(const unsigned int*)&f16[(long)s3 * 128 + lane * 2];
    ax += bf_lo(w0); ay += bf_hi(w0);
    ax += bf_lo(w1); ay += bf_hi(w1);
    ax += bf_lo(w2); ay += bf_hi(w2);
    ax += bf_lo(w3); ay += bf_hi(w3);
  }
  for (; j < end; ++j) {
    unsigned int w = *(const unsigned int*)&f16[(long)csr[j] * 128 + lane * 2];
    ax += bf_lo(w); ay += bf_hi(w);
  }
  float iv = inv[n];
  unsigned int packed = ((unsigned int)f2bf(ay * iv) << 16) | f2bf(ax * iv);
  *(unsigned int*)&out16[(long)n * 128 + lane * 2] = packed;
}

// ---------------- MFMA fused layer 2 + u/v (KERNEL UNDER TEST) ----------------
// z = mean2@w2l + b2l + h@w2r (fp32 acc); z->bf16 via XOR-swizzled LDS;
// u = z@dw1[:128] -> u16 ; v = z@dw1[128:] -> v16.
// Layout facts: A row = lane&15, k = 8*(lane>>4)+j (shared bijection with B);
// B from W^T [n][k] with n = tile + lane&15; C/D col = lane&15, row = 4*(lane>>4)+reg.
__global__ __launch_bounds__(256) void k_l2uv(
    const unsigned short* __restrict__ m2, const unsigned short* __restrict__ h16,
    const unsigned short* __restrict__ w2lt, const unsigned short* __restrict__ w2rt,
    const float* __restrict__ b2l, const unsigned short* __restrict__ dw1t,
    unsigned short* __restrict__ u16, unsigned short* __restrict__ v16) {
  __shared__ unsigned short s_z[64 * 128];  // 16 KB
  char* zb = (char*)s_z;
  const int l = threadIdx.x & 63;
  const int w = threadIdx.x >> 6;
  const int cl = l & 15;
  const int kh = l >> 4;
  const int row0 = blockIdx.x * 64 + w * 16;
  int arow = row0 + cl; if (arow >= N_NODES) arow = N_NODES - 1;

  f32x4 acc[8];
#pragma unroll
  for (int nt = 0; nt < 8; ++nt) acc[nt] = (f32x4){0.f, 0.f, 0.f, 0.f};

#pragma unroll
  for (int s = 0; s < 4; ++s) {
    bf16x8 am = *(const bf16x8*)(m2 + (long)arow * 128 + s * 32 + kh * 8);
    bf16x8 ah = *(const bf16x8*)(h16 + (long)arow * 128 + s * 32 + kh * 8);
#pragma unroll
    for (int nt = 0; nt < 8; ++nt) {
      bf16x8 bl = *(const bf16x8*)(w2lt + (long)(nt * 16 + cl) * 128 + s * 32 + kh * 8);
      bf16x8 br = *(const bf16x8*)(w2rt + (long)(nt * 16 + cl) * 128 + s * 32 + kh * 8);
      acc[nt] = __builtin_amdgcn_mfma_f32_16x16x32_bf16(am, bl, acc[nt], 0, 0, 0);
      acc[nt] = __builtin_amdgcn_mfma_f32_16x16x32_bf16(ah, br, acc[nt], 0, 0, 0);
    }
  }

  // z (+bias) -> LDS bf16, swizzle: byte ^= (row&7)<<4
#pragma unroll
  for (int nt = 0; nt < 8; ++nt) {
    float b = b2l[nt * 16 + cl];
#pragma unroll
    for (int i = 0; i < 4; ++i) {
      int zr = w * 16 + kh * 4 + i;
      int byte = (zr * 256 + (nt * 16 + cl) * 2) ^ ((zr & 7) << 4);
      *(unsigned short*)(zb + byte) = f2bf(acc[nt][i] + b);
    }
  }
  __syncthreads();

  f32x4 au[8], av[8];
#pragma unroll
  for (int nt = 0; nt < 8; ++nt) {
    au[nt] = (f32x4){0.f, 0.f, 0.f, 0.f};
    av[nt] = (f32x4){0.f, 0.f, 0.f, 0.f};
  }

#pragma unroll
  for (int s = 0; s < 4; ++s) {
    int zr = w * 16 + cl;
    int byte = (zr * 256 + s * 64 + kh * 16) ^ ((zr & 7) << 4);
    bf16x8 az = *(const bf16x8*)(zb + byte);
#pragma unroll
    for (int nt = 0; nt < 8; ++nt) {
      bf16x8 bu = *(const bf16x8*)(dw1t + (long)(nt * 16 + cl) * 128 + s * 32 + kh * 8);
      bf16x8 bv = *(const bf16x8*)(dw1t + (long)((nt + 8) * 16 + cl) * 128 + s * 32 + kh * 8);
      au[nt] = __builtin_amdgcn_mfma_f32_16x16x32_bf16(az, bu, au[nt], 0, 0, 0);
      av[nt] = __builtin_amdgcn_mfma_f32_16x16x32_bf16(az, bv, av[nt], 0, 0, 0);
    }
  }

#pragma unroll
  for (int nt = 0; nt < 8; ++nt) {
#pragma unroll
    for (int i = 0; i < 4; ++i) {
      int r = row0 + kh * 4 + i;
      if (r < N_NODES) {
        long o = (long)r * 128 + nt * 16 + cl;
        u16[o] = f2bf(au[nt][i]);
        v16[o] = f2bf(av[nt][i]);
      }
    }
  }
}

// ---------------- per-label-edge decoder (bf16 u,v) ----------------
__global__ __launch_bounds__(256) void k_edge(const int* __restrict__ ls,
                                              const int* __restrict__ ld,
                                              const unsigned short* __restrict__ u16,
                                              const unsigned short* __restrict__ v16,
                                              const float* __restrict__ db1,
                                              const float* __restrict__ dw2,
                                              const float* __restrict__ db2,
                                              float* __restrict__ out) {
  int lane = threadIdx.x & 63;
  long e = (long)blockIdx.x * 4 + (threadIdx.x >> 6);  // grid exact: 125000*4
  int s = ls[e], d = ld[e];
  unsigned int uu = *(const unsigned int*)&u16[(long)s * 128 + lane * 2];
  unsigned int vv = *(const unsigned int*)&v16[(long)d * 128 + lane * 2];
  const float2 b = *(const float2*)&db1[lane * 2];
  const float2 w = *(const float2*)&dw2[lane * 2];
  float h0 = fmaxf(bf_lo(uu) + bf_lo(vv) + b.x, 0.0f);
  float h1 = fmaxf(bf_hi(uu) + bf_hi(vv) + b.y, 0.0f);
  float sum = h0 * w.x + h1 * w.y;
#pragma unroll
  for (int o = 32; o > 0; o >>= 1) sum += __shfl_down(sum, o);
  if (lane == 0) out[e] = sum + db2[0];
}

extern "C" void kernel_launch(void* const* d_in, const int* in_sizes, int n_in,
                              void* d_out, int out_size, void* d_ws, size_t ws_size,
                              hipStream_t stream) {
  const float* x   = (const float*)d_in[0];
  const int*   ei  = (const int*)d_in[1];
  const int*   eli = (const int*)d_in[2];
  const float* w1l = (const float*)d_in[3];
  const float* b1l = (const float*)d_in[4];
  const float* w1r = (const float*)d_in[5];
  const float* w2l = (const float*)d_in[6];
  const float* b2l = (const float*)d_in[7];
  const float* w2r = (const float*)d_in[8];
  const float* dw1 = (const float*)d_in[9];
  const float* db1 = (const float*)d_in[10];
  const float* dw2 = (const float*)d_in[11];
  const float* db2 = (const float*)d_in[12];
  float* out = (float*)d_out;

  // ---- workspace layout (byte offsets, 16B aligned) ----
  char* wsb = (char*)d_ws;
  float* inv    = (float*)(wsb + 0);              // 400000
  int*   deg_i  = (int*)(wsb + 400000);           // 400000 (also cursor)
  int*   rowptr = (int*)(wsb + 800000);           // 400032
  int*   csr    = (int*)(wsb + 1200032);          // 6400000
  unsigned short* h16  = (unsigned short*)(wsb + 7600032);    // 25.6 MB
  unsigned short* m2   = (unsigned short*)(wsb + 33200032);   // 25.6 MB
  unsigned short* u16  = (unsigned short*)(wsb + 58800032);   // 25.6 MB
  unsigned short* v16  = (unsigned short*)(wsb + 84400032);   // 25.6 MB
  unsigned short* w2lt = (unsigned short*)(wsb + 110000032);  // 32768
  unsigned short* w2rt = (unsigned short*)(wsb + 110032800);  // 32768
  unsigned short* dw1t = (unsigned short*)(wsb + 110065568);  // 65536
  float* cbuf   = (float*)(wsb + 110131104);      // 25.6 MB (mean1 fp32) -> 135.73 MB total

  const int* srcp = ei;
  const int* dstp = ei + N_EDGES;
  const int* lsp  = eli;
  const int* ldp  = eli + N_LBL;

  // ---- CSR build + weight prep ----
  hipMemsetAsync(deg_i, 0, N_NODES * sizeof(int), stream);
  k_deg<<<N_EDGES / 256, 256, 0, stream>>>(dstp, deg_i);
  k_scan<<<1, 1024, 0, stream>>>(deg_i, rowptr, deg_i /*cursor*/, inv);
  k_fill<<<N_EDGES / 256, 256, 0, stream>>>(srcp, dstp, deg_i /*cursor*/, csr);
  k_prep_w<<<256, 256, 0, stream>>>(w2l, w2r, dw1, w2lt, w2rt, dw1t);

  // ---- layer 1: mean1 -> cbuf (fp32); h -> h16 (bf16) ----
  k_agg64<<<N_NODES / 4, 256, 0, stream>>>(rowptr, csr, x, inv, cbuf);
  k_l1<<<(N_NODES + 63) / 64, 256, 0, stream>>>(cbuf, x, w1l, b1l, w1r, h16);

  // ---- layer 2 + u/v (MFMA, under test) ----
  k_agg128<<<N_NODES / 4, 256, 0, stream>>>(rowptr, csr, h16, inv, m2);
  k_l2uv<<<(N_NODES + 63) / 64, 256, 0, stream>>>(m2, h16, w2lt, w2rt, b2l, dw1t, u16, v16);

  // ---- decoder edge MLP ----
  k_edge<<<N_LBL / 4, 256, 0, stream>>>(lsp, ldp, u16, v16, db1, dw2, db2, out);
}

// Round 10
// 648.159 us; speedup vs baseline: 1.4469x; 1.1075x over previous
//
#include <hip/hip_runtime.h>

#define N_NODES 100000
#define D_IN 64
#define HID 128
#define N_EDGES 1600000
#define N_LBL 500000

typedef __attribute__((ext_vector_type(8))) short bf16x8;
typedef __attribute__((ext_vector_type(4))) float f32x4;

// ---- bf16 helpers (RNE) ----
__device__ inline unsigned short f2bf(float f) {
  unsigned int u = __float_as_uint(f);
  return (unsigned short)((u + 0x7FFFu + ((u >> 16) & 1u)) >> 16);
}
__device__ inline float bf_lo(unsigned int w) { return __uint_as_float(w << 16); }
__device__ inline float bf_hi(unsigned int w) { return __uint_as_float(w & 0xFFFF0000u); }

// ---------------- degree histogram (int) ----------------
__global__ __launch_bounds__(256) void k_deg(const int* __restrict__ dst,
                                             int* __restrict__ deg) {
  int e = blockIdx.x * 256 + threadIdx.x;
  if (e < N_EDGES) atomicAdd(&deg[dst[e]], 1);
}

// ---------------- scan + inv (single block). cursor aliases deg. ----------------
__global__ __launch_bounds__(1024) void k_scan(const int* deg,
                                               int* __restrict__ rowptr,
                                               int* cursor,
                                               float* __restrict__ inv) {
  __shared__ int s_wsum[16];
  __shared__ int s_carry;
  const int lane = threadIdx.x & 63;
  const int wid = threadIdx.x >> 6;
  if (threadIdx.x == 0) s_carry = 0;
  __syncthreads();
  for (int base = 0; base < N_NODES; base += 1024) {
    int i = base + threadIdx.x;
    int v = (i < N_NODES) ? deg[i] : 0;
    int x = v;
#pragma unroll
    for (int off = 1; off < 64; off <<= 1) {
      int t = __shfl_up(x, off);
      if (lane >= off) x += t;
    }
    if (lane == 63) s_wsum[wid] = x;
    __syncthreads();
    if (wid == 0 && lane < 16) {
      int ws = s_wsum[lane];
      int y = ws;
#pragma unroll
      for (int off = 1; off < 16; off <<= 1) {
        int t = __shfl_up(y, off);
        if (lane >= off) y += t;
      }
      s_wsum[lane] = y - ws;
    }
    __syncthreads();
    int t = s_carry + s_wsum[wid] + (x - v);
    if (i < N_NODES) {
      rowptr[i] = t;
      cursor[i] = t;
      inv[i] = v > 0 ? 1.0f / (float)v : 0.0f;
    }
    __syncthreads();
    if (threadIdx.x == 1023) s_carry = t + v;
    __syncthreads();
  }
  if (threadIdx.x == 0) rowptr[N_NODES] = s_carry;
}

// ---------------- CSR fill ----------------
__global__ __launch_bounds__(256) void k_fill(const int* __restrict__ src,
                                              const int* __restrict__ dst,
                                              int* cursor,
                                              int* __restrict__ csr) {
  int e = blockIdx.x * 256 + threadIdx.x;
  if (e < N_EDGES) {
    int pos = atomicAdd(&cursor[dst[e]], 1);
    csr[pos] = src[e];
  }
}

// ---------------- prep: x -> bf16; all weights -> bf16 transposed [n][k] ----------------
// threads: 1.6M (x16, 4 f/thr) + 8192 + 8192 + 16384 + 16384 + 32768 = 1681920
__global__ __launch_bounds__(256) void k_prep(
    const float* __restrict__ x, const float* __restrict__ w1l,
    const float* __restrict__ w1r, const float* __restrict__ w2l,
    const float* __restrict__ w2r, const float* __restrict__ dw1,
    unsigned short* __restrict__ x16, unsigned short* __restrict__ w1lt,
    unsigned short* __restrict__ w1rt, unsigned short* __restrict__ w2lt,
    unsigned short* __restrict__ w2rt, unsigned short* __restrict__ dw1t) {
  long gid = (long)blockIdx.x * 256 + threadIdx.x;
  if (gid < 1600000) {
    long i = gid * 4;
    float4 v = *(const float4*)&x[i];
    ushort4 q = {f2bf(v.x), f2bf(v.y), f2bf(v.z), f2bf(v.w)};
    *(ushort4*)&x16[i] = q;
    return;
  }
  long idx = gid - 1600000;
  if (idx < 8192) { int n = idx >> 6, k = idx & 63; w1lt[idx] = f2bf(w1l[k * 128 + n]); return; }
  idx -= 8192;
  if (idx < 8192) { int n = idx >> 6, k = idx & 63; w1rt[idx] = f2bf(w1r[k * 128 + n]); return; }
  idx -= 8192;
  if (idx < 16384) { int n = idx >> 7, k = idx & 127; w2lt[idx] = f2bf(w2l[k * 128 + n]); return; }
  idx -= 16384;
  if (idx < 16384) { int n = idx >> 7, k = idx & 127; w2rt[idx] = f2bf(w2r[k * 128 + n]); return; }
  idx -= 16384;
  if (idx < 32768) {
    int n = idx >> 7, k = idx & 127;
    dw1t[idx] = f2bf(n < 128 ? dw1[k * 128 + n] : dw1[(k + 128) * 128 + (n - 128)]);
  }
}

// ---------------- gather aggregation D=64 (bf16 in/out): wave per node ----------------
__global__ __launch_bounds__(256) void k_agg64(const int* __restrict__ rowptr,
                                               const int* __restrict__ csr,
                                               const unsigned short* __restrict__ f16,
                                               const float* __restrict__ inv,
                                               unsigned short* __restrict__ out16) {
  const int lane = threadIdx.x & 63;
  const int n = blockIdx.x * 4 + (threadIdx.x >> 6);
  const int beg = rowptr[n], end = rowptr[n + 1];
  float acc = 0.0f;
  int j = beg;
  for (; j + 4 <= end; j += 4) {
    int s0 = csr[j], s1 = csr[j + 1], s2 = csr[j + 2], s3 = csr[j + 3];
    float f0 = bf_lo((unsigned int)f16[(long)s0 * 64 + lane]);
    float f1 = bf_lo((unsigned int)f16[(long)s1 * 64 + lane]);
    float f2 = bf_lo((unsigned int)f16[(long)s2 * 64 + lane]);
    float f3 = bf_lo((unsigned int)f16[(long)s3 * 64 + lane]);
    acc += f0; acc += f1; acc += f2; acc += f3;
  }
  for (; j < end; ++j) acc += bf_lo((unsigned int)f16[(long)csr[j] * 64 + lane]);
  out16[(long)n * 64 + lane] = f2bf(acc * inv[n]);
}

// ---------------- gather aggregation D=128 (bf16 in, bf16 out) ----------------
__global__ __launch_bounds__(256) void k_agg128(const int* __restrict__ rowptr,
                                                const int* __restrict__ csr,
                                                const unsigned short* __restrict__ f16,
                                                const float* __restrict__ inv,
                                                unsigned short* __restrict__ out16) {
  const int lane = threadIdx.x & 63;
  const int n = blockIdx.x * 4 + (threadIdx.x >> 6);
  const int beg = rowptr[n], end = rowptr[n + 1];
  float ax = 0.0f, ay = 0.0f;
  int j = beg;
  for (; j + 4 <= end; j += 4) {
    int s0 = csr[j], s1 = csr[j + 1], s2 = csr[j + 2], s3 = csr[j + 3];
    unsigned int w0 = *(const unsigned int*)&f16[(long)s0 * 128 + lane * 2];
    unsigned int w1 = *(const unsigned int*)&f16[(long)s1 * 128 + lane * 2];
    unsigned int w2 = *(const unsigned int*)&f16[(long)s2 * 128 + lane * 2];
    unsigned int w3 = *(const unsigned int*)&f16[(long)s3 * 128 + lane * 2];
    ax += bf_lo(w0); ay += bf_hi(w0);
    ax += bf_lo(w1); ay += bf_hi(w1);
    ax += bf_lo(w2); ay += bf_hi(w2);
    ax += bf_lo(w3); ay += bf_hi(w3);
  }
  for (; j < end; ++j) {
    unsigned int w = *(const unsigned int*)&f16[(long)csr[j] * 128 + lane * 2];
    ax += bf_lo(w); ay += bf_hi(w);
  }
  float iv = inv[n];
  unsigned int packed = ((unsigned int)f2bf(ay * iv) << 16) | f2bf(ax * iv);
  *(unsigned int*)&out16[(long)n * 128 + lane * 2] = packed;
}

// ---------------- MFMA layer 1: h16 = relu(mean1@w1l + b1l + x@w1r) ----------------
// 4 waves/block, 32 rows/wave (2 A-tiles) -> each B-load feeds 4 MFMAs.
__global__ __launch_bounds__(256) void k_l1(
    const unsigned short* __restrict__ m1, const unsigned short* __restrict__ x16,
    const unsigned short* __restrict__ w1lt, const unsigned short* __restrict__ w1rt,
    const float* __restrict__ b1l, unsigned short* __restrict__ h16) {
  const int l = threadIdx.x & 63;
  const int w = threadIdx.x >> 6;
  const int cl = l & 15;
  const int kh = l >> 4;
  const int wrow0 = blockIdx.x * 128 + w * 32;  // grid 782, tail guarded
  int ar0 = wrow0 + cl;      if (ar0 >= N_NODES) ar0 = N_NODES - 1;
  int ar1 = wrow0 + 16 + cl; if (ar1 >= N_NODES) ar1 = N_NODES - 1;

  f32x4 acc[2][8];
#pragma unroll
  for (int t = 0; t < 2; ++t)
#pragma unroll
    for (int nt = 0; nt < 8; ++nt) acc[t][nt] = (f32x4){0.f, 0.f, 0.f, 0.f};

#pragma unroll
  for (int s = 0; s < 2; ++s) {
    const int ko = s * 32 + kh * 8;
    bf16x8 am0 = *(const bf16x8*)(m1 + (long)ar0 * 64 + ko);
    bf16x8 ax0 = *(const bf16x8*)(x16 + (long)ar0 * 64 + ko);
    bf16x8 am1 = *(const bf16x8*)(m1 + (long)ar1 * 64 + ko);
    bf16x8 ax1 = *(const bf16x8*)(x16 + (long)ar1 * 64 + ko);
#pragma unroll
    for (int nt = 0; nt < 8; ++nt) {
      bf16x8 bl = *(const bf16x8*)(w1lt + (long)(nt * 16 + cl) * 64 + ko);
      bf16x8 br = *(const bf16x8*)(w1rt + (long)(nt * 16 + cl) * 64 + ko);
      acc[0][nt] = __builtin_amdgcn_mfma_f32_16x16x32_bf16(am0, bl, acc[0][nt], 0, 0, 0);
      acc[0][nt] = __builtin_amdgcn_mfma_f32_16x16x32_bf16(ax0, br, acc[0][nt], 0, 0, 0);
      acc[1][nt] = __builtin_amdgcn_mfma_f32_16x16x32_bf16(am1, bl, acc[1][nt], 0, 0, 0);
      acc[1][nt] = __builtin_amdgcn_mfma_f32_16x16x32_bf16(ax1, br, acc[1][nt], 0, 0, 0);
    }
  }

#pragma unroll
  for (int t = 0; t < 2; ++t)
#pragma unroll
    for (int nt = 0; nt < 8; ++nt) {
      float b = b1l[nt * 16 + cl];
#pragma unroll
      for (int i = 0; i < 4; ++i) {
        int r = wrow0 + t * 16 + kh * 4 + i;
        if (r < N_NODES)
          h16[(long)r * 128 + nt * 16 + cl] = f2bf(fmaxf(acc[t][nt][i] + b, 0.0f));
      }
    }
}

// ---------------- MFMA fused layer 2 + u/v (32 rows/wave, two-pass u/v) ----------------
__global__ __launch_bounds__(256) void k_l2uv(
    const unsigned short* __restrict__ m2, const unsigned short* __restrict__ h16,
    const unsigned short* __restrict__ w2lt, const unsigned short* __restrict__ w2rt,
    const float* __restrict__ b2l, const unsigned short* __restrict__ dw1t,
    unsigned short* __restrict__ u16, unsigned short* __restrict__ v16) {
  __shared__ unsigned short s_z[128 * 128];  // 32 KB, XOR-swizzled rows
  char* zb = (char*)s_z;
  const int l = threadIdx.x & 63;
  const int w = threadIdx.x >> 6;
  const int cl = l & 15;
  const int kh = l >> 4;
  const int wrow0 = blockIdx.x * 128 + w * 32;  // grid 782, tail guarded
  int ar0 = wrow0 + cl;      if (ar0 >= N_NODES) ar0 = N_NODES - 1;
  int ar1 = wrow0 + 16 + cl; if (ar1 >= N_NODES) ar1 = N_NODES - 1;

  f32x4 acc[2][8];
#pragma unroll
  for (int t = 0; t < 2; ++t)
#pragma unroll
    for (int nt = 0; nt < 8; ++nt) acc[t][nt] = (f32x4){0.f, 0.f, 0.f, 0.f};

#pragma unroll
  for (int s = 0; s < 4; ++s) {
    const int ko = s * 32 + kh * 8;
    bf16x8 am0 = *(const bf16x8*)(m2 + (long)ar0 * 128 + ko);
    bf16x8 ah0 = *(const bf16x8*)(h16 + (long)ar0 * 128 + ko);
    bf16x8 am1 = *(const bf16x8*)(m2 + (long)ar1 * 128 + ko);
    bf16x8 ah1 = *(const bf16x8*)(h16 + (long)ar1 * 128 + ko);
#pragma unroll
    for (int nt = 0; nt < 8; ++nt) {
      bf16x8 bl = *(const bf16x8*)(w2lt + (long)(nt * 16 + cl) * 128 + ko);
      bf16x8 br = *(const bf16x8*)(w2rt + (long)(nt * 16 + cl) * 128 + ko);
      acc[0][nt] = __builtin_amdgcn_mfma_f32_16x16x32_bf16(am0, bl, acc[0][nt], 0, 0, 0);
      acc[0][nt] = __builtin_amdgcn_mfma_f32_16x16x32_bf16(ah0, br, acc[0][nt], 0, 0, 0);
      acc[1][nt] = __builtin_amdgcn_mfma_f32_16x16x32_bf16(am1, bl, acc[1][nt], 0, 0, 0);
      acc[1][nt] = __builtin_amdgcn_mfma_f32_16x16x32_bf16(ah1, br, acc[1][nt], 0, 0, 0);
    }
  }

  // z (+bias) -> LDS bf16, swizzle: byte ^= (row&7)<<4
#pragma unroll
  for (int t = 0; t < 2; ++t)
#pragma unroll
    for (int nt = 0; nt < 8; ++nt) {
      float b = b2l[nt * 16 + cl];
#pragma unroll
      for (int i = 0; i < 4; ++i) {
        int zr = w * 32 + t * 16 + kh * 4 + i;
        int byte = (zr * 256 + (nt * 16 + cl) * 2) ^ ((zr & 7) << 4);
        *(unsigned short*)(zb + byte) = f2bf(acc[t][nt][i] + b);
      }
    }
  __syncthreads();

  // ---- pass u ----
  f32x4 uu[2][8];
#pragma unroll
  for (int t = 0; t < 2; ++t)
#pragma unroll
    for (int nt = 0; nt < 8; ++nt) uu[t][nt] = (f32x4){0.f, 0.f, 0.f, 0.f};
#pragma unroll
  for (int s = 0; s < 4; ++s) {
    const int zr0 = w * 32 + cl;
    const int zr1 = w * 32 + 16 + cl;
    bf16x8 az0 = *(const bf16x8*)(zb + ((zr0 * 256 + s * 64 + kh * 16) ^ ((zr0 & 7) << 4)));
    bf16x8 az1 = *(const bf16x8*)(zb + ((zr1 * 256 + s * 64 + kh * 16) ^ ((zr1 & 7) << 4)));
#pragma unroll
    for (int nt = 0; nt < 8; ++nt) {
      bf16x8 bu = *(const bf16x8*)(dw1t + (long)(nt * 16 + cl) * 128 + s * 32 + kh * 8);
      uu[0][nt] = __builtin_amdgcn_mfma_f32_16x16x32_bf16(az0, bu, uu[0][nt], 0, 0, 0);
      uu[1][nt] = __builtin_amdgcn_mfma_f32_16x16x32_bf16(az1, bu, uu[1][nt], 0, 0, 0);
    }
  }
#pragma unroll
  for (int t = 0; t < 2; ++t)
#pragma unroll
    for (int nt = 0; nt < 8; ++nt)
#pragma unroll
      for (int i = 0; i < 4; ++i) {
        int r = wrow0 + t * 16 + kh * 4 + i;
        if (r < N_NODES) u16[(long)r * 128 + nt * 16 + cl] = f2bf(uu[t][nt][i]);
      }

  // ---- pass v (reuse uu registers) ----
#pragma unroll
  for (int t = 0; t < 2; ++t)
#pragma unroll
    for (int nt = 0; nt < 8; ++nt) uu[t][nt] = (f32x4){0.f, 0.f, 0.f, 0.f};
#pragma unroll
  for (int s = 0; s < 4; ++s) {
    const int zr0 = w * 32 + cl;
    const int zr1 = w * 32 + 16 + cl;
    bf16x8 az0 = *(const bf16x8*)(zb + ((zr0 * 256 + s * 64 + kh * 16) ^ ((zr0 & 7) << 4)));
    bf16x8 az1 = *(const bf16x8*)(zb + ((zr1 * 256 + s * 64 + kh * 16) ^ ((zr1 & 7) << 4)));
#pragma unroll
    for (int nt = 0; nt < 8; ++nt) {
      bf16x8 bv = *(const bf16x8*)(dw1t + (long)((nt + 8) * 16 + cl) * 128 + s * 32 + kh * 8);
      uu[0][nt] = __builtin_amdgcn_mfma_f32_16x16x32_bf16(az0, bv, uu[0][nt], 0, 0, 0);
      uu[1][nt] = __builtin_amdgcn_mfma_f32_16x16x32_bf16(az1, bv, uu[1][nt], 0, 0, 0);
    }
  }
#pragma unroll
  for (int t = 0; t < 2; ++t)
#pragma unroll
    for (int nt = 0; nt < 8; ++nt)
#pragma unroll
      for (int i = 0; i < 4; ++i) {
        int r = wrow0 + t * 16 + kh * 4 + i;
        if (r < N_NODES) v16[(long)r * 128 + nt * 16 + cl] = f2bf(uu[t][nt][i]);
      }
}

// ---------------- per-label-edge decoder (bf16 u,v) ----------------
__global__ __launch_bounds__(256) void k_edge(const int* __restrict__ ls,
                                              const int* __restrict__ ld,
                                              const unsigned short* __restrict__ u16,
                                              const unsigned short* __restrict__ v16,
                                              const float* __restrict__ db1,
                                              const float* __restrict__ dw2,
                                              const float* __restrict__ db2,
                                              float* __restrict__ out) {
  int lane = threadIdx.x & 63;
  long e = (long)blockIdx.x * 4 + (threadIdx.x >> 6);  // grid exact: 125000*4
  int s = ls[e], d = ld[e];
  unsigned int uu = *(const unsigned int*)&u16[(long)s * 128 + lane * 2];
  unsigned int vv = *(const unsigned int*)&v16[(long)d * 128 + lane * 2];
  const float2 b = *(const float2*)&db1[lane * 2];
  const float2 w = *(const float2*)&dw2[lane * 2];
  float h0 = fmaxf(bf_lo(uu) + bf_lo(vv) + b.x, 0.0f);
  float h1 = fmaxf(bf_hi(uu) + bf_hi(vv) + b.y, 0.0f);
  float sum = h0 * w.x + h1 * w.y;
#pragma unroll
  for (int o = 32; o > 0; o >>= 1) sum += __shfl_down(sum, o);
  if (lane == 0) out[e] = sum + db2[0];
}

extern "C" void kernel_launch(void* const* d_in, const int* in_sizes, int n_in,
                              void* d_out, int out_size, void* d_ws, size_t ws_size,
                              hipStream_t stream) {
  const float* x   = (const float*)d_in[0];
  const int*   ei  = (const int*)d_in[1];
  const int*   eli = (const int*)d_in[2];
  const float* w1l = (const float*)d_in[3];
  const float* b1l = (const float*)d_in[4];
  const float* w1r = (const float*)d_in[5];
  const float* w2l = (const float*)d_in[6];
  const float* b2l = (const float*)d_in[7];
  const float* w2r = (const float*)d_in[8];
  const float* dw1 = (const float*)d_in[9];
  const float* db1 = (const float*)d_in[10];
  const float* dw2 = (const float*)d_in[11];
  const float* db2 = (const float*)d_in[12];
  float* out = (float*)d_out;

  // ---- workspace layout (byte offsets, 16B aligned) ----
  // u16 aliases x16+m1 (both dead before k_l2uv writes u16).
  char* wsb = (char*)d_ws;
  float* inv    = (float*)(wsb + 0);              // 400000
  int*   deg_i  = (int*)(wsb + 400000);           // 400000 (also cursor)
  int*   rowptr = (int*)(wsb + 800000);           // 400032
  int*   csr    = (int*)(wsb + 1200032);          // 6400000
  unsigned short* x16  = (unsigned short*)(wsb + 7600032);    // 12.8 MB
  unsigned short* m1   = (unsigned short*)(wsb + 20400032);   // 12.8 MB
  unsigned short* u16  = (unsigned short*)(wsb + 7600032);    // 25.6 MB (aliases x16+m1)
  unsigned short* h16  = (unsigned short*)(wsb + 33200032);   // 25.6 MB
  unsigned short* m2   = (unsigned short*)(wsb + 58800032);   // 25.6 MB
  unsigned short* v16  = (unsigned short*)(wsb + 84400032);   // 25.6 MB
  unsigned short* w1lt = (unsigned short*)(wsb + 110000032);  // 16384
  unsigned short* w1rt = (unsigned short*)(wsb + 110016416);  // 16384
  unsigned short* w2lt = (unsigned short*)(wsb + 110032800);  // 32768
  unsigned short* w2rt = (unsigned short*)(wsb + 110065568);  // 32768
  unsigned short* dw1t = (unsigned short*)(wsb + 110098336);  // 65536 -> ends 110163872

  const int* srcp = ei;
  const int* dstp = ei + N_EDGES;
  const int* lsp  = eli;
  const int* ldp  = eli + N_LBL;

  // ---- CSR build + prep ----
  hipMemsetAsync(deg_i, 0, N_NODES * sizeof(int), stream);
  k_deg<<<N_EDGES / 256, 256, 0, stream>>>(dstp, deg_i);
  k_scan<<<1, 1024, 0, stream>>>(deg_i, rowptr, deg_i /*cursor*/, inv);
  k_fill<<<N_EDGES / 256, 256, 0, stream>>>(srcp, dstp, deg_i /*cursor*/, csr);
  k_prep<<<(1681920 + 255) / 256, 256, 0, stream>>>(
      x, w1l, w1r, w2l, w2r, dw1, x16, w1lt, w1rt, w2lt, w2rt, dw1t);

  // ---- layer 1 (all MFMA) ----
  k_agg64<<<N_NODES / 4, 256, 0, stream>>>(rowptr, csr, x16, inv, m1);
  k_l1<<<(N_NODES + 127) / 128, 256, 0, stream>>>(m1, x16, w1lt, w1rt, b1l, h16);

  // ---- layer 2 + u/v (MFMA) ----
  k_agg128<<<N_NODES / 4, 256, 0, stream>>>(rowptr, csr, h16, inv, m2);
  k_l2uv<<<(N_NODES + 127) / 128, 256, 0, stream>>>(m2, h16, w2lt, w2rt, b2l, dw1t, u16, v16);

  // ---- decoder edge MLP ----
  k_edge<<<N_LBL / 4, 256, 0, stream>>>(lsp, ldp, u16, v16, db1, dw2, db2, out);
}

// Round 11
// 573.570 us; speedup vs baseline: 1.6351x; 1.1300x over previous
//
#include <hip/hip_runtime.h>

#define N_NODES 100000
#define D_IN 64
#define HID 128
#define N_EDGES 1600000
#define N_LBL 500000
#define NBUCK 196  // ceil(100000/512) buckets of 512 dst nodes

typedef __attribute__((ext_vector_type(8))) short bf16x8;
typedef __attribute__((ext_vector_type(4))) float f32x4;

// ---- bf16 helpers (RNE) ----
__device__ inline unsigned short f2bf(float f) {
  unsigned int u = __float_as_uint(f);
  return (unsigned short)((u + 0x7FFFu + ((u >> 16) & 1u)) >> 16);
}
__device__ inline float bf_lo(unsigned int w) { return __uint_as_float(w << 16); }
__device__ inline float bf_hi(unsigned int w) { return __uint_as_float(w & 0xFFFF0000u); }

// ---------------- degree histogram (int) ----------------
__global__ __launch_bounds__(256) void k_deg(const int* __restrict__ dst,
                                             int* __restrict__ deg) {
  int e = blockIdx.x * 256 + threadIdx.x;
  if (e < N_EDGES) atomicAdd(&deg[dst[e]], 1);
}

// ---------------- scan + inv + bucket-cursor init (single block) ----------------
__global__ __launch_bounds__(1024) void k_scan(const int* __restrict__ deg,
                                               int* __restrict__ rowptr,
                                               int* __restrict__ gcursor,
                                               float* __restrict__ inv) {
  __shared__ int s_wsum[16];
  __shared__ int s_carry;
  const int lane = threadIdx.x & 63;
  const int wid = threadIdx.x >> 6;
  if (threadIdx.x == 0) s_carry = 0;
  __syncthreads();
  for (int base = 0; base < N_NODES; base += 1024) {
    int i = base + threadIdx.x;
    int v = (i < N_NODES) ? deg[i] : 0;
    int x = v;
#pragma unroll
    for (int off = 1; off < 64; off <<= 1) {
      int t = __shfl_up(x, off);
      if (lane >= off) x += t;
    }
    if (lane == 63) s_wsum[wid] = x;
    __syncthreads();
    if (wid == 0 && lane < 16) {
      int ws = s_wsum[lane];
      int y = ws;
#pragma unroll
      for (int off = 1; off < 16; off <<= 1) {
        int t = __shfl_up(y, off);
        if (lane >= off) y += t;
      }
      s_wsum[lane] = y - ws;
    }
    __syncthreads();
    int t = s_carry + s_wsum[wid] + (x - v);
    if (i < N_NODES) {
      rowptr[i] = t;
      inv[i] = v > 0 ? 1.0f / (float)v : 0.0f;
    }
    __syncthreads();
    if (threadIdx.x == 1023) s_carry = t + v;
    __syncthreads();
  }
  if (threadIdx.x == 0) rowptr[N_NODES] = s_carry;
  __syncthreads();
  // bucket cursors = bucket start positions in edge space
  for (int t = threadIdx.x; t < NBUCK; t += 1024) gcursor[t] = rowptr[t << 9];
}

// ---------------- bin edges by dst bucket (LDS-aggregated reservations) ----------------
// 4096 edges/block; packed word = (src<<9) | (dst&511).
__global__ __launch_bounds__(256) void k_bin(const int* __restrict__ src,
                                             const int* __restrict__ dst,
                                             int* __restrict__ gcursor,
                                             int* __restrict__ binned) {
  __shared__ int hist[NBUCK];
  __shared__ int base[NBUCK];
  const int tid = threadIdx.x;
  const int e0 = blockIdx.x * 4096 + tid;
  for (int t = tid; t < NBUCK; t += 256) hist[t] = 0;
  __syncthreads();

  int w[16], bk[16], rk[16];
#pragma unroll
  for (int i = 0; i < 16; ++i) {
    int e = e0 + i * 256;
    if (e < N_EDGES) {
      int s = src[e], d = dst[e];
      bk[i] = d >> 9;
      w[i] = (s << 9) | (d & 511);
      rk[i] = atomicAdd(&hist[bk[i]], 1);
    } else {
      bk[i] = -1;
    }
  }
  __syncthreads();
  for (int t = tid; t < NBUCK; t += 256)
    base[t] = hist[t] > 0 ? atomicAdd(&gcursor[t], hist[t]) : 0;
  __syncthreads();
#pragma unroll
  for (int i = 0; i < 16; ++i)
    if (bk[i] >= 0) binned[base[bk[i]] + rk[i]] = w[i];
}

// ---------------- CSR fill from binned edges: block per bucket, LDS cursors ----------------
__global__ __launch_bounds__(256) void k_fill2(const int* __restrict__ rowptr,
                                               const int* __restrict__ binned,
                                               int* __restrict__ csr) {
  __shared__ int lcur[512];
  const int b = blockIdx.x;
  const int nb = b << 9;
  const int nn = min(512, N_NODES - nb);
  for (int i = threadIdx.x; i < nn; i += 256) lcur[i] = rowptr[nb + i];
  __syncthreads();
  const int beg = rowptr[nb], end = rowptr[nb + nn];
  for (int e = beg + threadIdx.x; e < end; e += 256) {
    int w = binned[e];
    int pos = atomicAdd(&lcur[w & 511], 1);
    csr[pos] = w >> 9;
  }
}

// ---------------- prep: x -> bf16; all weights -> bf16 transposed [n][k] ----------------
__global__ __launch_bounds__(256) void k_prep(
    const float* __restrict__ x, const float* __restrict__ w1l,
    const float* __restrict__ w1r, const float* __restrict__ w2l,
    const float* __restrict__ w2r, const float* __restrict__ dw1,
    unsigned short* __restrict__ x16, unsigned short* __restrict__ w1lt,
    unsigned short* __restrict__ w1rt, unsigned short* __restrict__ w2lt,
    unsigned short* __restrict__ w2rt, unsigned short* __restrict__ dw1t) {
  long gid = (long)blockIdx.x * 256 + threadIdx.x;
  if (gid < 1600000) {
    long i = gid * 4;
    float4 v = *(const float4*)&x[i];
    ushort4 q = {f2bf(v.x), f2bf(v.y), f2bf(v.z), f2bf(v.w)};
    *(ushort4*)&x16[i] = q;
    return;
  }
  long idx = gid - 1600000;
  if (idx < 8192) { int n = idx >> 6, k = idx & 63; w1lt[idx] = f2bf(w1l[k * 128 + n]); return; }
  idx -= 8192;
  if (idx < 8192) { int n = idx >> 6, k = idx & 63; w1rt[idx] = f2bf(w1r[k * 128 + n]); return; }
  idx -= 8192;
  if (idx < 16384) { int n = idx >> 7, k = idx & 127; w2lt[idx] = f2bf(w2l[k * 128 + n]); return; }
  idx -= 16384;
  if (idx < 16384) { int n = idx >> 7, k = idx & 127; w2rt[idx] = f2bf(w2r[k * 128 + n]); return; }
  idx -= 16384;
  if (idx < 32768) {
    int n = idx >> 7, k = idx & 127;
    dw1t[idx] = f2bf(n < 128 ? dw1[k * 128 + n] : dw1[(k + 128) * 128 + (n - 128)]);
  }
}

// ---------------- gather aggregation D=64 (bf16 in/out): wave per node ----------------
__global__ __launch_bounds__(256) void k_agg64(const int* __restrict__ rowptr,
                                               const int* __restrict__ csr,
                                               const unsigned short* __restrict__ f16,
                                               const float* __restrict__ inv,
                                               unsigned short* __restrict__ out16) {
  const int lane = threadIdx.x & 63;
  const int n = blockIdx.x * 4 + (threadIdx.x >> 6);
  const int beg = rowptr[n], end = rowptr[n + 1];
  float acc = 0.0f;
  int j = beg;
  for (; j + 4 <= end; j += 4) {
    int s0 = csr[j], s1 = csr[j + 1], s2 = csr[j + 2], s3 = csr[j + 3];
    float f0 = bf_lo((unsigned int)f16[(long)s0 * 64 + lane]);
    float f1 = bf_lo((unsigned int)f16[(long)s1 * 64 + lane]);
    float f2 = bf_lo((unsigned int)f16[(long)s2 * 64 + lane]);
    float f3 = bf_lo((unsigned int)f16[(long)s3 * 64 + lane]);
    acc += f0; acc += f1; acc += f2; acc += f3;
  }
  for (; j < end; ++j) acc += bf_lo((unsigned int)f16[(long)csr[j] * 64 + lane]);
  out16[(long)n * 64 + lane] = f2bf(acc * inv[n]);
}

// ---------------- gather aggregation D=128 (bf16 in, bf16 out) ----------------
__global__ __launch_bounds__(256) void k_agg128(const int* __restrict__ rowptr,
                                                const int* __restrict__ csr,
                                                const unsigned short* __restrict__ f16,
                                                const float* __restrict__ inv,
                                                unsigned short* __restrict__ out16) {
  const int lane = threadIdx.x & 63;
  const int n = blockIdx.x * 4 + (threadIdx.x >> 6);
  const int beg = rowptr[n], end = rowptr[n + 1];
  float ax = 0.0f, ay = 0.0f;
  int j = beg;
  for (; j + 4 <= end; j += 4) {
    int s0 = csr[j], s1 = csr[j + 1], s2 = csr[j + 2], s3 = csr[j + 3];
    unsigned int w0 = *(const unsigned int*)&f16[(long)s0 * 128 + lane * 2];
    unsigned int w1 = *(const unsigned int*)&f16[(long)s1 * 128 + lane * 2];
    unsigned int w2 = *(const unsigned int*)&f16[(long)s2 * 128 + lane * 2];
    unsigned int w3 = *(const unsigned int*)&f16[(long)s3 * 128 + lane * 2];
    ax += bf_lo(w0); ay += bf_hi(w0);
    ax += bf_lo(w1); ay += bf_hi(w1);
    ax += bf_lo(w2); ay += bf_hi(w2);
    ax += bf_lo(w3); ay += bf_hi(w3);
  }
  for (; j < end; ++j) {
    unsigned int w = *(const unsigned int*)&f16[(long)csr[j] * 128 + lane * 2];
    ax += bf_lo(w); ay += bf_hi(w);
  }
  float iv = inv[n];
  unsigned int packed = ((unsigned int)f2bf(ay * iv) << 16) | f2bf(ax * iv);
  *(unsigned int*)&out16[(long)n * 128 + lane * 2] = packed;
}

// ---------------- MFMA layer 1: h16 = relu(mean1@w1l + b1l + x@w1r) ----------------
__global__ __launch_bounds__(256) void k_l1(
    const unsigned short* __restrict__ m1, const unsigned short* __restrict__ x16,
    const unsigned short* __restrict__ w1lt, const unsigned short* __restrict__ w1rt,
    const float* __restrict__ b1l, unsigned short* __restrict__ h16) {
  const int l = threadIdx.x & 63;
  const int w = threadIdx.x >> 6;
  const int cl = l & 15;
  const int kh = l >> 4;
  const int wrow0 = blockIdx.x * 128 + w * 32;
  int ar0 = wrow0 + cl;      if (ar0 >= N_NODES) ar0 = N_NODES - 1;
  int ar1 = wrow0 + 16 + cl; if (ar1 >= N_NODES) ar1 = N_NODES - 1;

  f32x4 acc[2][8];
#pragma unroll
  for (int t = 0; t < 2; ++t)
#pragma unroll
    for (int nt = 0; nt < 8; ++nt) acc[t][nt] = (f32x4){0.f, 0.f, 0.f, 0.f};

#pragma unroll
  for (int s = 0; s < 2; ++s) {
    const int ko = s * 32 + kh * 8;
    bf16x8 am0 = *(const bf16x8*)(m1 + (long)ar0 * 64 + ko);
    bf16x8 ax0 = *(const bf16x8*)(x16 + (long)ar0 * 64 + ko);
    bf16x8 am1 = *(const bf16x8*)(m1 + (long)ar1 * 64 + ko);
    bf16x8 ax1 = *(const bf16x8*)(x16 + (long)ar1 * 64 + ko);
#pragma unroll
    for (int nt = 0; nt < 8; ++nt) {
      bf16x8 bl = *(const bf16x8*)(w1lt + (long)(nt * 16 + cl) * 64 + ko);
      bf16x8 br = *(const bf16x8*)(w1rt + (long)(nt * 16 + cl) * 64 + ko);
      acc[0][nt] = __builtin_amdgcn_mfma_f32_16x16x32_bf16(am0, bl, acc[0][nt], 0, 0, 0);
      acc[0][nt] = __builtin_amdgcn_mfma_f32_16x16x32_bf16(ax0, br, acc[0][nt], 0, 0, 0);
      acc[1][nt] = __builtin_amdgcn_mfma_f32_16x16x32_bf16(am1, bl, acc[1][nt], 0, 0, 0);
      acc[1][nt] = __builtin_amdgcn_mfma_f32_16x16x32_bf16(ax1, br, acc[1][nt], 0, 0, 0);
    }
  }

#pragma unroll
  for (int t = 0; t < 2; ++t)
#pragma unroll
    for (int nt = 0; nt < 8; ++nt) {
      float b = b1l[nt * 16 + cl];
#pragma unroll
      for (int i = 0; i < 4; ++i) {
        int r = wrow0 + t * 16 + kh * 4 + i;
        if (r < N_NODES)
          h16[(long)r * 128 + nt * 16 + cl] = f2bf(fmaxf(acc[t][nt][i] + b, 0.0f));
      }
    }
}

// ---------------- MFMA fused layer 2 + u/v (32 rows/wave, two-pass u/v) ----------------
__global__ __launch_bounds__(256) void k_l2uv(
    const unsigned short* __restrict__ m2, const unsigned short* __restrict__ h16,
    const unsigned short* __restrict__ w2lt, const unsigned short* __restrict__ w2rt,
    const float* __restrict__ b2l, const unsigned short* __restrict__ dw1t,
    unsigned short* __restrict__ u16, unsigned short* __restrict__ v16) {
  __shared__ unsigned short s_z[128 * 128];  // 32 KB, XOR-swizzled rows
  char* zb = (char*)s_z;
  const int l = threadIdx.x & 63;
  const int w = threadIdx.x >> 6;
  const int cl = l & 15;
  const int kh = l >> 4;
  const int wrow0 = blockIdx.x * 128 + w * 32;
  int ar0 = wrow0 + cl;      if (ar0 >= N_NODES) ar0 = N_NODES - 1;
  int ar1 = wrow0 + 16 + cl; if (ar1 >= N_NODES) ar1 = N_NODES - 1;

  f32x4 acc[2][8];
#pragma unroll
  for (int t = 0; t < 2; ++t)
#pragma unroll
    for (int nt = 0; nt < 8; ++nt) acc[t][nt] = (f32x4){0.f, 0.f, 0.f, 0.f};

#pragma unroll
  for (int s = 0; s < 4; ++s) {
    const int ko = s * 32 + kh * 8;
    bf16x8 am0 = *(const bf16x8*)(m2 + (long)ar0 * 128 + ko);
    bf16x8 ah0 = *(const bf16x8*)(h16 + (long)ar0 * 128 + ko);
    bf16x8 am1 = *(const bf16x8*)(m2 + (long)ar1 * 128 + ko);
    bf16x8 ah1 = *(const bf16x8*)(h16 + (long)ar1 * 128 + ko);
#pragma unroll
    for (int nt = 0; nt < 8; ++nt) {
      bf16x8 bl = *(const bf16x8*)(w2lt + (long)(nt * 16 + cl) * 128 + ko);
      bf16x8 br = *(const bf16x8*)(w2rt + (long)(nt * 16 + cl) * 128 + ko);
      acc[0][nt] = __builtin_amdgcn_mfma_f32_16x16x32_bf16(am0, bl, acc[0][nt], 0, 0, 0);
      acc[0][nt] = __builtin_amdgcn_mfma_f32_16x16x32_bf16(ah0, br, acc[0][nt], 0, 0, 0);
      acc[1][nt] = __builtin_amdgcn_mfma_f32_16x16x32_bf16(am1, bl, acc[1][nt], 0, 0, 0);
      acc[1][nt] = __builtin_amdgcn_mfma_f32_16x16x32_bf16(ah1, br, acc[1][nt], 0, 0, 0);
    }
  }

#pragma unroll
  for (int t = 0; t < 2; ++t)
#pragma unroll
    for (int nt = 0; nt < 8; ++nt) {
      float b = b2l[nt * 16 + cl];
#pragma unroll
      for (int i = 0; i < 4; ++i) {
        int zr = w * 32 + t * 16 + kh * 4 + i;
        int byte = (zr * 256 + (nt * 16 + cl) * 2) ^ ((zr & 7) << 4);
        *(unsigned short*)(zb + byte) = f2bf(acc[t][nt][i] + b);
      }
    }
  __syncthreads();

  // ---- pass u ----
  f32x4 uu[2][8];
#pragma unroll
  for (int t = 0; t < 2; ++t)
#pragma unroll
    for (int nt = 0; nt < 8; ++nt) uu[t][nt] = (f32x4){0.f, 0.f, 0.f, 0.f};
#pragma unroll
  for (int s = 0; s < 4; ++s) {
    const int zr0 = w * 32 + cl;
    const int zr1 = w * 32 + 16 + cl;
    bf16x8 az0 = *(const bf16x8*)(zb + ((zr0 * 256 + s * 64 + kh * 16) ^ ((zr0 & 7) << 4)));
    bf16x8 az1 = *(const bf16x8*)(zb + ((zr1 * 256 + s * 64 + kh * 16) ^ ((zr1 & 7) << 4)));
#pragma unroll
    for (int nt = 0; nt < 8; ++nt) {
      bf16x8 bu = *(const bf16x8*)(dw1t + (long)(nt * 16 + cl) * 128 + s * 32 + kh * 8);
      uu[0][nt] = __builtin_amdgcn_mfma_f32_16x16x32_bf16(az0, bu, uu[0][nt], 0, 0, 0);
      uu[1][nt] = __builtin_amdgcn_mfma_f32_16x16x32_bf16(az1, bu, uu[1][nt], 0, 0, 0);
    }
  }
#pragma unroll
  for (int t = 0; t < 2; ++t)
#pragma unroll
    for (int nt = 0; nt < 8; ++nt)
#pragma unroll
      for (int i = 0; i < 4; ++i) {
        int r = wrow0 + t * 16 + kh * 4 + i;
        if (r < N_NODES) u16[(long)r * 128 + nt * 16 + cl] = f2bf(uu[t][nt][i]);
      }

  // ---- pass v (reuse uu registers) ----
#pragma unroll
  for (int t = 0; t < 2; ++t)
#pragma unroll
    for (int nt = 0; nt < 8; ++nt) uu[t][nt] = (f32x4){0.f, 0.f, 0.f, 0.f};
#pragma unroll
  for (int s = 0; s < 4; ++s) {
    const int zr0 = w * 32 + cl;
    const int zr1 = w * 32 + 16 + cl;
    bf16x8 az0 = *(const bf16x8*)(zb + ((zr0 * 256 + s * 64 + kh * 16) ^ ((zr0 & 7) << 4)));
    bf16x8 az1 = *(const bf16x8*)(zb + ((zr1 * 256 + s * 64 + kh * 16) ^ ((zr1 & 7) << 4)));
#pragma unroll
    for (int nt = 0; nt < 8; ++nt) {
      bf16x8 bv = *(const bf16x8*)(dw1t + (long)((nt + 8) * 16 + cl) * 128 + s * 32 + kh * 8);
      uu[0][nt] = __builtin_amdgcn_mfma_f32_16x16x32_bf16(az0, bv, uu[0][nt], 0, 0, 0);
      uu[1][nt] = __builtin_amdgcn_mfma_f32_16x16x32_bf16(az1, bv, uu[1][nt], 0, 0, 0);
    }
  }
#pragma unroll
  for (int t = 0; t < 2; ++t)
#pragma unroll
    for (int nt = 0; nt < 8; ++nt)
#pragma unroll
      for (int i = 0; i < 4; ++i) {
        int r = wrow0 + t * 16 + kh * 4 + i;
        if (r < N_NODES) v16[(long)r * 128 + nt * 16 + cl] = f2bf(uu[t][nt][i]);
      }
}

// ---------------- per-label-edge decoder (bf16 u,v) ----------------
__global__ __launch_bounds__(256) void k_edge(const int* __restrict__ ls,
                                              const int* __restrict__ ld,
                                              const unsigned short* __restrict__ u16,
                                              const unsigned short* __restrict__ v16,
                                              const float* __restrict__ db1,
                                              const float* __restrict__ dw2,
                                              const float* __restrict__ db2,
                                              float* __restrict__ out) {
  int lane = threadIdx.x & 63;
  long e = (long)blockIdx.x * 4 + (threadIdx.x >> 6);
  int s = ls[e], d = ld[e];
  unsigned int uu = *(const unsigned int*)&u16[(long)s * 128 + lane * 2];
  unsigned int vv = *(const unsigned int*)&v16[(long)d * 128 + lane * 2];
  const float2 b = *(const float2*)&db1[lane * 2];
  const float2 w = *(const float2*)&dw2[lane * 2];
  float h0 = fmaxf(bf_lo(uu) + bf_lo(vv) + b.x, 0.0f);
  float h1 = fmaxf(bf_hi(uu) + bf_hi(vv) + b.y, 0.0f);
  float sum = h0 * w.x + h1 * w.y;
#pragma unroll
  for (int o = 32; o > 0; o >>= 1) sum += __shfl_down(sum, o);
  if (lane == 0) out[e] = sum + db2[0];
}

extern "C" void kernel_launch(void* const* d_in, const int* in_sizes, int n_in,
                              void* d_out, int out_size, void* d_ws, size_t ws_size,
                              hipStream_t stream) {
  const float* x   = (const float*)d_in[0];
  const int*   ei  = (const int*)d_in[1];
  const int*   eli = (const int*)d_in[2];
  const float* w1l = (const float*)d_in[3];
  const float* b1l = (const float*)d_in[4];
  const float* w1r = (const float*)d_in[5];
  const float* w2l = (const float*)d_in[6];
  const float* b2l = (const float*)d_in[7];
  const float* w2r = (const float*)d_in[8];
  const float* dw1 = (const float*)d_in[9];
  const float* db1 = (const float*)d_in[10];
  const float* dw2 = (const float*)d_in[11];
  const float* db2 = (const float*)d_in[12];
  float* out = (float*)d_out;

  // ---- workspace layout (byte offsets, 16B aligned) ----
  // u16 aliases x16+m1 (both dead before k_l2uv writes u16).
  char* wsb = (char*)d_ws;
  float* inv     = (float*)(wsb + 0);              // 400000
  int*   deg_i   = (int*)(wsb + 400000);           // 400000
  int*   rowptr  = (int*)(wsb + 800000);           // 400032
  int*   gcursor = (int*)(wsb + 1200032);          // 1024
  int*   csr     = (int*)(wsb + 1201056);          // 6400000
  int*   binned  = (int*)(wsb + 7601056);          // 6400000
  unsigned short* x16  = (unsigned short*)(wsb + 14001056);   // 12.8 MB
  unsigned short* m1   = (unsigned short*)(wsb + 26801056);   // 12.8 MB
  unsigned short* u16  = (unsigned short*)(wsb + 14001056);   // 25.6 MB (aliases x16+m1)
  unsigned short* h16  = (unsigned short*)(wsb + 39601056);   // 25.6 MB
  unsigned short* m2   = (unsigned short*)(wsb + 65201056);   // 25.6 MB
  unsigned short* v16  = (unsigned short*)(wsb + 90801056);   // 25.6 MB
  unsigned short* w1lt = (unsigned short*)(wsb + 116401056);  // 16384
  unsigned short* w1rt = (unsigned short*)(wsb + 116417440);  // 16384
  unsigned short* w2lt = (unsigned short*)(wsb + 116433824);  // 32768
  unsigned short* w2rt = (unsigned short*)(wsb + 116466592);  // 32768
  unsigned short* dw1t = (unsigned short*)(wsb + 116499360);  // 65536 -> ends 116564896

  const int* srcp = ei;
  const int* dstp = ei + N_EDGES;
  const int* lsp  = eli;
  const int* ldp  = eli + N_LBL;

  // ---- CSR build (binned, write-dense) + prep ----
  hipMemsetAsync(deg_i, 0, N_NODES * sizeof(int), stream);
  k_deg<<<N_EDGES / 256, 256, 0, stream>>>(dstp, deg_i);
  k_scan<<<1, 1024, 0, stream>>>(deg_i, rowptr, gcursor, inv);
  k_bin<<<(N_EDGES + 4095) / 4096, 256, 0, stream>>>(srcp, dstp, gcursor, binned);
  k_fill2<<<NBUCK, 256, 0, stream>>>(rowptr, binned, csr);
  k_prep<<<(1681920 + 255) / 256, 256, 0, stream>>>(
      x, w1l, w1r, w2l, w2r, dw1, x16, w1lt, w1rt, w2lt, w2rt, dw1t);

  // ---- layer 1 (MFMA) ----
  k_agg64<<<N_NODES / 4, 256, 0, stream>>>(rowptr, csr, x16, inv, m1);
  k_l1<<<(N_NODES + 127) / 128, 256, 0, stream>>>(m1, x16, w1lt, w1rt, b1l, h16);

  // ---- layer 2 + u/v (MFMA) ----
  k_agg128<<<N_NODES / 4, 256, 0, stream>>>(rowptr, csr, h16, inv, m2);
  k_l2uv<<<(N_NODES + 127) / 128, 256, 0, stream>>>(m2, h16, w2lt, w2rt, b2l, dw1t, u16, v16);

  // ---- decoder edge MLP ----
  k_edge<<<N_LBL / 4, 256, 0, stream>>>(lsp, ldp, u16, v16, db1, dw2, db2, out);
}

// Round 12
// 477.705 us; speedup vs baseline: 1.9632x; 1.2007x over previous
//
#include <hip/hip_runtime.h>

#define N_NODES 100000
#define D_IN 64
#define HID 128
#define N_EDGES 1600000
#define N_LBL 500000
#define NBUCK 196   // ceil(100000/512) buckets of 512 dst nodes
#define NSCANB 98   // ceil(100000/1024) scan blocks

typedef __attribute__((ext_vector_type(8))) short bf16x8;
typedef __attribute__((ext_vector_type(4))) float f32x4;

// ---- bf16 helpers (RNE) ----
__device__ inline unsigned short f2bf(float f) {
  unsigned int u = __float_as_uint(f);
  return (unsigned short)((u + 0x7FFFu + ((u >> 16) & 1u)) >> 16);
}
__device__ inline float bf_lo(unsigned int w) { return __uint_as_float(w << 16); }
__device__ inline float bf_hi(unsigned int w) { return __uint_as_float(w & 0xFFFF0000u); }

// ---------------- degree histogram (int) ----------------
__global__ __launch_bounds__(256) void k_deg(const int* __restrict__ dst,
                                             int* __restrict__ deg) {
  int e = blockIdx.x * 256 + threadIdx.x;
  if (e < N_EDGES) atomicAdd(&deg[dst[e]], 1);
}

// ---------------- scan phase A: per-block local scan + block totals + inv ----------------
__global__ __launch_bounds__(1024) void k_scan_a(const int* __restrict__ deg,
                                                 int* __restrict__ rowptr,
                                                 float* __restrict__ inv,
                                                 int* __restrict__ bsum) {
  __shared__ int s_wsum[16];
  const int lane = threadIdx.x & 63;
  const int wid = threadIdx.x >> 6;
  const int i = blockIdx.x * 1024 + threadIdx.x;
  int v = (i < N_NODES) ? deg[i] : 0;
  int x = v;
#pragma unroll
  for (int off = 1; off < 64; off <<= 1) {
    int t = __shfl_up(x, off);
    if (lane >= off) x += t;
  }
  if (lane == 63) s_wsum[wid] = x;
  __syncthreads();
  if (wid == 0 && lane < 16) {
    int ws = s_wsum[lane];
    int y = ws;
#pragma unroll
    for (int off = 1; off < 16; off <<= 1) {
      int t = __shfl_up(y, off);
      if (lane >= off) y += t;
    }
    s_wsum[lane] = y - ws;  // exclusive wave offsets
    if (lane == 15) bsum[blockIdx.x] = y;  // block total
  }
  __syncthreads();
  if (i < N_NODES) {
    rowptr[i] = s_wsum[wid] + x - v;  // block-local exclusive prefix
    inv[i] = v > 0 ? 1.0f / (float)v : 0.0f;
  }
}

// ---------------- scan phase B: exclusive scan of 98 block totals (in place) ----------------
__global__ __launch_bounds__(128) void k_scan_b(int* __restrict__ bsum,
                                                int* __restrict__ rowptr) {
  __shared__ int s_w;
  const int tid = threadIdx.x;
  const int lane = tid & 63, wid = tid >> 6;
  int v = (tid < NSCANB) ? bsum[tid] : 0;
  int x = v;
#pragma unroll
  for (int off = 1; off < 64; off <<= 1) {
    int t = __shfl_up(x, off);
    if (lane >= off) x += t;
  }
  if (wid == 0 && lane == 63) s_w = x;
  __syncthreads();
  int incl = x + (wid == 1 ? s_w : 0);
  if (tid < NSCANB) bsum[tid] = incl - v;  // exclusive offset
  if (tid == NSCANB - 1) rowptr[N_NODES] = incl;  // grand total
}

// ---------------- scan phase C: add block offsets + bucket cursor init ----------------
__global__ __launch_bounds__(1024) void k_scan_c(int* __restrict__ rowptr,
                                                 const int* __restrict__ bsum,
                                                 int* __restrict__ gcursor) {
  const int i = blockIdx.x * 1024 + threadIdx.x;
  if (i < N_NODES) {
    int r = rowptr[i] + bsum[blockIdx.x];
    rowptr[i] = r;
    if ((i & 511) == 0) gcursor[i >> 9] = r;
  }
}

// ---------------- bin edges by dst bucket (LDS-aggregated reservations) ----------------
// 4096 edges/block; packed word = (src<<9) | (dst&511).
__global__ __launch_bounds__(256) void k_bin(const int* __restrict__ src,
                                             const int* __restrict__ dst,
                                             int* __restrict__ gcursor,
                                             int* __restrict__ binned) {
  __shared__ int hist[NBUCK];
  __shared__ int base[NBUCK];
  const int tid = threadIdx.x;
  const int e0 = blockIdx.x * 4096 + tid;
  for (int t = tid; t < NBUCK; t += 256) hist[t] = 0;
  __syncthreads();

  int w[16], bk[16], rk[16];
#pragma unroll
  for (int i = 0; i < 16; ++i) {
    int e = e0 + i * 256;
    if (e < N_EDGES) {
      int s = src[e], d = dst[e];
      bk[i] = d >> 9;
      w[i] = (s << 9) | (d & 511);
      rk[i] = atomicAdd(&hist[bk[i]], 1);
    } else {
      bk[i] = -1;
    }
  }
  __syncthreads();
  for (int t = tid; t < NBUCK; t += 256)
    base[t] = hist[t] > 0 ? atomicAdd(&gcursor[t], hist[t]) : 0;
  __syncthreads();
#pragma unroll
  for (int i = 0; i < 16; ++i)
    if (bk[i] >= 0) binned[base[bk[i]] + rk[i]] = w[i];
}

// ---------------- CSR fill from binned edges: block per bucket, LDS cursors ----------------
__global__ __launch_bounds__(256) void k_fill2(const int* __restrict__ rowptr,
                                               const int* __restrict__ binned,
                                               int* __restrict__ csr) {
  __shared__ int lcur[512];
  const int b = blockIdx.x;
  const int nb = b << 9;
  const int nn = min(512, N_NODES - nb);
  for (int i = threadIdx.x; i < nn; i += 256) lcur[i] = rowptr[nb + i];
  __syncthreads();
  const int beg = rowptr[nb], end = rowptr[nb + nn];
  for (int e = beg + threadIdx.x; e < end; e += 256) {
    int w = binned[e];
    int pos = atomicAdd(&lcur[w & 511], 1);
    csr[pos] = w >> 9;
  }
}

// ---------------- prep: x -> bf16; all weights -> bf16 transposed [n][k] ----------------
__global__ __launch_bounds__(256) void k_prep(
    const float* __restrict__ x, const float* __restrict__ w1l,
    const float* __restrict__ w1r, const float* __restrict__ w2l,
    const float* __restrict__ w2r, const float* __restrict__ dw1,
    unsigned short* __restrict__ x16, unsigned short* __restrict__ w1lt,
    unsigned short* __restrict__ w1rt, unsigned short* __restrict__ w2lt,
    unsigned short* __restrict__ w2rt, unsigned short* __restrict__ dw1t) {
  long gid = (long)blockIdx.x * 256 + threadIdx.x;
  if (gid < 1600000) {
    long i = gid * 4;
    float4 v = *(const float4*)&x[i];
    ushort4 q = {f2bf(v.x), f2bf(v.y), f2bf(v.z), f2bf(v.w)};
    *(ushort4*)&x16[i] = q;
    return;
  }
  long idx = gid - 1600000;
  if (idx < 8192) { int n = idx >> 6, k = idx & 63; w1lt[idx] = f2bf(w1l[k * 128 + n]); return; }
  idx -= 8192;
  if (idx < 8192) { int n = idx >> 6, k = idx & 63; w1rt[idx] = f2bf(w1r[k * 128 + n]); return; }
  idx -= 8192;
  if (idx < 16384) { int n = idx >> 7, k = idx & 127; w2lt[idx] = f2bf(w2l[k * 128 + n]); return; }
  idx -= 16384;
  if (idx < 16384) { int n = idx >> 7, k = idx & 127; w2rt[idx] = f2bf(w2r[k * 128 + n]); return; }
  idx -= 16384;
  if (idx < 32768) {
    int n = idx >> 7, k = idx & 127;
    dw1t[idx] = f2bf(n < 128 ? dw1[k * 128 + n] : dw1[(k + 128) * 128 + (n - 128)]);
  }
}

// ---------------- gather aggregation D=64 (bf16 in/out): wave per node ----------------
__global__ __launch_bounds__(256) void k_agg64(const int* __restrict__ rowptr,
                                               const int* __restrict__ csr,
                                               const unsigned short* __restrict__ f16,
                                               const float* __restrict__ inv,
                                               unsigned short* __restrict__ out16) {
  const int lane = threadIdx.x & 63;
  const int n = blockIdx.x * 4 + (threadIdx.x >> 6);
  const int beg = rowptr[n], end = rowptr[n + 1];
  float acc = 0.0f;
  int j = beg;
  for (; j + 4 <= end; j += 4) {
    int s0 = csr[j], s1 = csr[j + 1], s2 = csr[j + 2], s3 = csr[j + 3];
    float f0 = bf_lo((unsigned int)f16[(long)s0 * 64 + lane]);
    float f1 = bf_lo((unsigned int)f16[(long)s1 * 64 + lane]);
    float f2 = bf_lo((unsigned int)f16[(long)s2 * 64 + lane]);
    float f3 = bf_lo((unsigned int)f16[(long)s3 * 64 + lane]);
    acc += f0; acc += f1; acc += f2; acc += f3;
  }
  for (; j < end; ++j) acc += bf_lo((unsigned int)f16[(long)csr[j] * 64 + lane]);
  out16[(long)n * 64 + lane] = f2bf(acc * inv[n]);
}

// ---------------- gather aggregation D=128 (bf16 in, bf16 out) ----------------
__global__ __launch_bounds__(256) void k_agg128(const int* __restrict__ rowptr,
                                                const int* __restrict__ csr,
                                                const unsigned short* __restrict__ f16,
                                                const float* __restrict__ inv,
                                                unsigned short* __restrict__ out16) {
  const int lane = threadIdx.x & 63;
  const int n = blockIdx.x * 4 + (threadIdx.x >> 6);
  const int beg = rowptr[n], end = rowptr[n + 1];
  float ax = 0.0f, ay = 0.0f;
  int j = beg;
  for (; j + 4 <= end; j += 4) {
    int s0 = csr[j], s1 = csr[j + 1], s2 = csr[j + 2], s3 = csr[j + 3];
    unsigned int w0 = *(const unsigned int*)&f16[(long)s0 * 128 + lane * 2];
    unsigned int w1 = *(const unsigned int*)&f16[(long)s1 * 128 + lane * 2];
    unsigned int w2 = *(const unsigned int*)&f16[(long)s2 * 128 + lane * 2];
    unsigned int w3 = *(const unsigned int*)&f16[(long)s3 * 128 + lane * 2];
    ax += bf_lo(w0); ay += bf_hi(w0);
    ax += bf_lo(w1); ay += bf_hi(w1);
    ax += bf_lo(w2); ay += bf_hi(w2);
    ax += bf_lo(w3); ay += bf_hi(w3);
  }
  for (; j < end; ++j) {
    unsigned int w = *(const unsigned int*)&f16[(long)csr[j] * 128 + lane * 2];
    ax += bf_lo(w); ay += bf_hi(w);
  }
  float iv = inv[n];
  unsigned int packed = ((unsigned int)f2bf(ay * iv) << 16) | f2bf(ax * iv);
  *(unsigned int*)&out16[(long)n * 128 + lane * 2] = packed;
}

// ---------------- MFMA layer 1: h16 = relu(mean1@w1l + b1l + x@w1r) ----------------
__global__ __launch_bounds__(256) void k_l1(
    const unsigned short* __restrict__ m1, const unsigned short* __restrict__ x16,
    const unsigned short* __restrict__ w1lt, const unsigned short* __restrict__ w1rt,
    const float* __restrict__ b1l, unsigned short* __restrict__ h16) {
  const int l = threadIdx.x & 63;
  const int w = threadIdx.x >> 6;
  const int cl = l & 15;
  const int kh = l >> 4;
  const int wrow0 = blockIdx.x * 128 + w * 32;
  int ar0 = wrow0 + cl;      if (ar0 >= N_NODES) ar0 = N_NODES - 1;
  int ar1 = wrow0 + 16 + cl; if (ar1 >= N_NODES) ar1 = N_NODES - 1;

  f32x4 acc[2][8];
#pragma unroll
  for (int t = 0; t < 2; ++t)
#pragma unroll
    for (int nt = 0; nt < 8; ++nt) acc[t][nt] = (f32x4){0.f, 0.f, 0.f, 0.f};

#pragma unroll
  for (int s = 0; s < 2; ++s) {
    const int ko = s * 32 + kh * 8;
    bf16x8 am0 = *(const bf16x8*)(m1 + (long)ar0 * 64 + ko);
    bf16x8 ax0 = *(const bf16x8*)(x16 + (long)ar0 * 64 + ko);
    bf16x8 am1 = *(const bf16x8*)(m1 + (long)ar1 * 64 + ko);
    bf16x8 ax1 = *(const bf16x8*)(x16 + (long)ar1 * 64 + ko);
#pragma unroll
    for (int nt = 0; nt < 8; ++nt) {
      bf16x8 bl = *(const bf16x8*)(w1lt + (long)(nt * 16 + cl) * 64 + ko);
      bf16x8 br = *(const bf16x8*)(w1rt + (long)(nt * 16 + cl) * 64 + ko);
      acc[0][nt] = __builtin_amdgcn_mfma_f32_16x16x32_bf16(am0, bl, acc[0][nt], 0, 0, 0);
      acc[0][nt] = __builtin_amdgcn_mfma_f32_16x16x32_bf16(ax0, br, acc[0][nt], 0, 0, 0);
      acc[1][nt] = __builtin_amdgcn_mfma_f32_16x16x32_bf16(am1, bl, acc[1][nt], 0, 0, 0);
      acc[1][nt] = __builtin_amdgcn_mfma_f32_16x16x32_bf16(ax1, br, acc[1][nt], 0, 0, 0);
    }
  }

#pragma unroll
  for (int t = 0; t < 2; ++t)
#pragma unroll
    for (int nt = 0; nt < 8; ++nt) {
      float b = b1l[nt * 16 + cl];
#pragma unroll
      for (int i = 0; i < 4; ++i) {
        int r = wrow0 + t * 16 + kh * 4 + i;
        if (r < N_NODES)
          h16[(long)r * 128 + nt * 16 + cl] = f2bf(fmaxf(acc[t][nt][i] + b, 0.0f));
      }
    }
}

// ---------------- MFMA fused layer 2 + u/v (32 rows/wave, two-pass u/v) ----------------
__global__ __launch_bounds__(256) void k_l2uv(
    const unsigned short* __restrict__ m2, const unsigned short* __restrict__ h16,
    const unsigned short* __restrict__ w2lt, const unsigned short* __restrict__ w2rt,
    const float* __restrict__ b2l, const unsigned short* __restrict__ dw1t,
    unsigned short* __restrict__ u16, unsigned short* __restrict__ v16) {
  __shared__ unsigned short s_z[128 * 128];  // 32 KB, XOR-swizzled rows
  char* zb = (char*)s_z;
  const int l = threadIdx.x & 63;
  const int w = threadIdx.x >> 6;
  const int cl = l & 15;
  const int kh = l >> 4;
  const int wrow0 = blockIdx.x * 128 + w * 32;
  int ar0 = wrow0 + cl;      if (ar0 >= N_NODES) ar0 = N_NODES - 1;
  int ar1 = wrow0 + 16 + cl; if (ar1 >= N_NODES) ar1 = N_NODES - 1;

  f32x4 acc[2][8];
#pragma unroll
  for (int t = 0; t < 2; ++t)
#pragma unroll
    for (int nt = 0; nt < 8; ++nt) acc[t][nt] = (f32x4){0.f, 0.f, 0.f, 0.f};

#pragma unroll
  for (int s = 0; s < 4; ++s) {
    const int ko = s * 32 + kh * 8;
    bf16x8 am0 = *(const bf16x8*)(m2 + (long)ar0 * 128 + ko);
    bf16x8 ah0 = *(const bf16x8*)(h16 + (long)ar0 * 128 + ko);
    bf16x8 am1 = *(const bf16x8*)(m2 + (long)ar1 * 128 + ko);
    bf16x8 ah1 = *(const bf16x8*)(h16 + (long)ar1 * 128 + ko);
#pragma unroll
    for (int nt = 0; nt < 8; ++nt) {
      bf16x8 bl = *(const bf16x8*)(w2lt + (long)(nt * 16 + cl) * 128 + ko);
      bf16x8 br = *(const bf16x8*)(w2rt + (long)(nt * 16 + cl) * 128 + ko);
      acc[0][nt] = __builtin_amdgcn_mfma_f32_16x16x32_bf16(am0, bl, acc[0][nt], 0, 0, 0);
      acc[0][nt] = __builtin_amdgcn_mfma_f32_16x16x32_bf16(ah0, br, acc[0][nt], 0, 0, 0);
      acc[1][nt] = __builtin_amdgcn_mfma_f32_16x16x32_bf16(am1, bl, acc[1][nt], 0, 0, 0);
      acc[1][nt] = __builtin_amdgcn_mfma_f32_16x16x32_bf16(ah1, br, acc[1][nt], 0, 0, 0);
    }
  }

#pragma unroll
  for (int t = 0; t < 2; ++t)
#pragma unroll
    for (int nt = 0; nt < 8; ++nt) {
      float b = b2l[nt * 16 + cl];
#pragma unroll
      for (int i = 0; i < 4; ++i) {
        int zr = w * 32 + t * 16 + kh * 4 + i;
        int byte = (zr * 256 + (nt * 16 + cl) * 2) ^ ((zr & 7) << 4);
        *(unsigned short*)(zb + byte) = f2bf(acc[t][nt][i] + b);
      }
    }
  __syncthreads();

  // ---- pass u ----
  f32x4 uu[2][8];
#pragma unroll
  for (int t = 0; t < 2; ++t)
#pragma unroll
    for (int nt = 0; nt < 8; ++nt) uu[t][nt] = (f32x4){0.f, 0.f, 0.f, 0.f};
#pragma unroll
  for (int s = 0; s < 4; ++s) {
    const int zr0 = w * 32 + cl;
    const int zr1 = w * 32 + 16 + cl;
    bf16x8 az0 = *(const bf16x8*)(zb + ((zr0 * 256 + s * 64 + kh * 16) ^ ((zr0 & 7) << 4)));
    bf16x8 az1 = *(const bf16x8*)(zb + ((zr1 * 256 + s * 64 + kh * 16) ^ ((zr1 & 7) << 4)));
#pragma unroll
    for (int nt = 0; nt < 8; ++nt) {
      bf16x8 bu = *(const bf16x8*)(dw1t + (long)(nt * 16 + cl) * 128 + s * 32 + kh * 8);
      uu[0][nt] = __builtin_amdgcn_mfma_f32_16x16x32_bf16(az0, bu, uu[0][nt], 0, 0, 0);
      uu[1][nt] = __builtin_amdgcn_mfma_f32_16x16x32_bf16(az1, bu, uu[1][nt], 0, 0, 0);
    }
  }
#pragma unroll
  for (int t = 0; t < 2; ++t)
#pragma unroll
    for (int nt = 0; nt < 8; ++nt)
#pragma unroll
      for (int i = 0; i < 4; ++i) {
        int r = wrow0 + t * 16 + kh * 4 + i;
        if (r < N_NODES) u16[(long)r * 128 + nt * 16 + cl] = f2bf(uu[t][nt][i]);
      }

  // ---- pass v (reuse uu registers) ----
#pragma unroll
  for (int t = 0; t < 2; ++t)
#pragma unroll
    for (int nt = 0; nt < 8; ++nt) uu[t][nt] = (f32x4){0.f, 0.f, 0.f, 0.f};
#pragma unroll
  for (int s = 0; s < 4; ++s) {
    const int zr0 = w * 32 + cl;
    const int zr1 = w * 32 + 16 + cl;
    bf16x8 az0 = *(const bf16x8*)(zb + ((zr0 * 256 + s * 64 + kh * 16) ^ ((zr0 & 7) << 4)));
    bf16x8 az1 = *(const bf16x8*)(zb + ((zr1 * 256 + s * 64 + kh * 16) ^ ((zr1 & 7) << 4)));
#pragma unroll
    for (int nt = 0; nt < 8; ++nt) {
      bf16x8 bv = *(const bf16x8*)(dw1t + (long)((nt + 8) * 16 + cl) * 128 + s * 32 + kh * 8);
      uu[0][nt] = __builtin_amdgcn_mfma_f32_16x16x32_bf16(az0, bv, uu[0][nt], 0, 0, 0);
      uu[1][nt] = __builtin_amdgcn_mfma_f32_16x16x32_bf16(az1, bv, uu[1][nt], 0, 0, 0);
    }
  }
#pragma unroll
  for (int t = 0; t < 2; ++t)
#pragma unroll
    for (int nt = 0; nt < 8; ++nt)
#pragma unroll
      for (int i = 0; i < 4; ++i) {
        int r = wrow0 + t * 16 + kh * 4 + i;
        if (r < N_NODES) v16[(long)r * 128 + nt * 16 + cl] = f2bf(uu[t][nt][i]);
      }
}

// ---------------- per-label-edge decoder (bf16 u,v) ----------------
__global__ __launch_bounds__(256) void k_edge(const int* __restrict__ ls,
                                              const int* __restrict__ ld,
                                              const unsigned short* __restrict__ u16,
                                              const unsigned short* __restrict__ v16,
                                              const float* __restrict__ db1,
                                              const float* __restrict__ dw2,
                                              const float* __restrict__ db2,
                                              float* __restrict__ out) {
  int lane = threadIdx.x & 63;
  long e = (long)blockIdx.x * 4 + (threadIdx.x >> 6);
  int s = ls[e], d = ld[e];
  unsigned int uu = *(const unsigned int*)&u16[(long)s * 128 + lane * 2];
  unsigned int vv = *(const unsigned int*)&v16[(long)d * 128 + lane * 2];
  const float2 b = *(const float2*)&db1[lane * 2];
  const float2 w = *(const float2*)&dw2[lane * 2];
  float h0 = fmaxf(bf_lo(uu) + bf_lo(vv) + b.x, 0.0f);
  float h1 = fmaxf(bf_hi(uu) + bf_hi(vv) + b.y, 0.0f);
  float sum = h0 * w.x + h1 * w.y;
#pragma unroll
  for (int o = 32; o > 0; o >>= 1) sum += __shfl_down(sum, o);
  if (lane == 0) out[e] = sum + db2[0];
}

extern "C" void kernel_launch(void* const* d_in, const int* in_sizes, int n_in,
                              void* d_out, int out_size, void* d_ws, size_t ws_size,
                              hipStream_t stream) {
  const float* x   = (const float*)d_in[0];
  const int*   ei  = (const int*)d_in[1];
  const int*   eli = (const int*)d_in[2];
  const float* w1l = (const float*)d_in[3];
  const float* b1l = (const float*)d_in[4];
  const float* w1r = (const float*)d_in[5];
  const float* w2l = (const float*)d_in[6];
  const float* b2l = (const float*)d_in[7];
  const float* w2r = (const float*)d_in[8];
  const float* dw1 = (const float*)d_in[9];
  const float* db1 = (const float*)d_in[10];
  const float* dw2 = (const float*)d_in[11];
  const float* db2 = (const float*)d_in[12];
  float* out = (float*)d_out;

  // ---- workspace layout (byte offsets, 16B aligned) ----
  // u16 aliases x16+m1 (both dead before k_l2uv writes u16).
  char* wsb = (char*)d_ws;
  float* inv     = (float*)(wsb + 0);              // 400000
  int*   deg_i   = (int*)(wsb + 400000);           // 400000
  int*   rowptr  = (int*)(wsb + 800000);           // 400032
  int*   gcursor = (int*)(wsb + 1200032);          // 1024
  int*   csr     = (int*)(wsb + 1201056);          // 6400000
  int*   binned  = (int*)(wsb + 7601056);          // 6400000
  unsigned short* x16  = (unsigned short*)(wsb + 14001056);   // 12.8 MB
  unsigned short* m1   = (unsigned short*)(wsb + 26801056);   // 12.8 MB
  unsigned short* u16  = (unsigned short*)(wsb + 14001056);   // 25.6 MB (aliases x16+m1)
  unsigned short* h16  = (unsigned short*)(wsb + 39601056);   // 25.6 MB
  unsigned short* m2   = (unsigned short*)(wsb + 65201056);   // 25.6 MB
  unsigned short* v16  = (unsigned short*)(wsb + 90801056);   // 25.6 MB
  unsigned short* w1lt = (unsigned short*)(wsb + 116401056);  // 16384
  unsigned short* w1rt = (unsigned short*)(wsb + 116417440);  // 16384
  unsigned short* w2lt = (unsigned short*)(wsb + 116433824);  // 32768
  unsigned short* w2rt = (unsigned short*)(wsb + 116466592);  // 32768
  unsigned short* dw1t = (unsigned short*)(wsb + 116499360);  // 65536
  int*   bsum    = (int*)(wsb + 116564896);        // 512 -> ends 116565408

  const int* srcp = ei;
  const int* dstp = ei + N_EDGES;
  const int* lsp  = eli;
  const int* ldp  = eli + N_LBL;

  // ---- CSR build (parallel scan + binned fill) + prep ----
  hipMemsetAsync(deg_i, 0, N_NODES * sizeof(int), stream);
  k_deg<<<N_EDGES / 256, 256, 0, stream>>>(dstp, deg_i);
  k_scan_a<<<NSCANB, 1024, 0, stream>>>(deg_i, rowptr, inv, bsum);
  k_scan_b<<<1, 128, 0, stream>>>(bsum, rowptr);
  k_scan_c<<<NSCANB, 1024, 0, stream>>>(rowptr, bsum, gcursor);
  k_bin<<<(N_EDGES + 4095) / 4096, 256, 0, stream>>>(srcp, dstp, gcursor, binned);
  k_fill2<<<NBUCK, 256, 0, stream>>>(rowptr, binned, csr);
  k_prep<<<(1681920 + 255) / 256, 256, 0, stream>>>(
      x, w1l, w1r, w2l, w2r, dw1, x16, w1lt, w1rt, w2lt, w2rt, dw1t);

  // ---- layer 1 (MFMA) ----
  k_agg64<<<N_NODES / 4, 256, 0, stream>>>(rowptr, csr, x16, inv, m1);
  k_l1<<<(N_NODES + 127) / 128, 256, 0, stream>>>(m1, x16, w1lt, w1rt, b1l, h16);

  // ---- layer 2 + u/v (MFMA) ----
  k_agg128<<<N_NODES / 4, 256, 0, stream>>>(rowptr, csr, h16, inv, m2);
  k_l2uv<<<(N_NODES + 127) / 128, 256, 0, stream>>>(m2, h16, w2lt, w2rt, b2l, dw1t, u16, v16);

  // ---- decoder edge MLP ----
  k_edge<<<N_LBL / 4, 256, 0, stream>>>(lsp, ldp, u16, v16, db1, dw2, db2, out);
}

// Round 13
// 453.933 us; speedup vs baseline: 2.0660x; 1.0524x over previous
//
#include <hip/hip_runtime.h>

#define N_NODES 100000
#define D_IN 64
#define HID 128
#define N_EDGES 1600000
#define N_LBL 500000
#define NBUCK 196   // ceil(100000/512) buckets of 512 dst nodes
#define NSCANB 98   // ceil(100000/1024) scan blocks
#define LCAP 3072   // label-edge bucket capacity (lambda=2560, sigma~51)

typedef __attribute__((ext_vector_type(8))) short bf16x8;
typedef __attribute__((ext_vector_type(4))) float f32x4;

// ---- bf16 helpers (RNE) ----
__device__ inline unsigned short f2bf(float f) {
  unsigned int u = __float_as_uint(f);
  return (unsigned short)((u + 0x7FFFu + ((u >> 16) & 1u)) >> 16);
}
__device__ inline float bf_lo(unsigned int w) { return __uint_as_float(w << 16); }
__device__ inline float bf_hi(unsigned int w) { return __uint_as_float(w & 0xFFFF0000u); }
__device__ inline float bfs(short s) {
  return __uint_as_float(((unsigned int)(unsigned short)s) << 16);
}

// ---------------- degree histogram (int) ----------------
__global__ __launch_bounds__(256) void k_deg(const int* __restrict__ dst,
                                             int* __restrict__ deg) {
  int e = blockIdx.x * 256 + threadIdx.x;
  if (e < N_EDGES) atomicAdd(&deg[dst[e]], 1);
}

// ---------------- scan phase A ----------------
__global__ __launch_bounds__(1024) void k_scan_a(const int* __restrict__ deg,
                                                 int* __restrict__ rowptr,
                                                 float* __restrict__ inv,
                                                 int* __restrict__ bsum) {
  __shared__ int s_wsum[16];
  const int lane = threadIdx.x & 63;
  const int wid = threadIdx.x >> 6;
  const int i = blockIdx.x * 1024 + threadIdx.x;
  int v = (i < N_NODES) ? deg[i] : 0;
  int x = v;
#pragma unroll
  for (int off = 1; off < 64; off <<= 1) {
    int t = __shfl_up(x, off);
    if (lane >= off) x += t;
  }
  if (lane == 63) s_wsum[wid] = x;
  __syncthreads();
  if (wid == 0 && lane < 16) {
    int ws = s_wsum[lane];
    int y = ws;
#pragma unroll
    for (int off = 1; off < 16; off <<= 1) {
      int t = __shfl_up(y, off);
      if (lane >= off) y += t;
    }
    s_wsum[lane] = y - ws;
    if (lane == 15) bsum[blockIdx.x] = y;
  }
  __syncthreads();
  if (i < N_NODES) {
    rowptr[i] = s_wsum[wid] + x - v;
    inv[i] = v > 0 ? 1.0f / (float)v : 0.0f;
  }
}

// ---------------- scan phase B ----------------
__global__ __launch_bounds__(128) void k_scan_b(int* __restrict__ bsum,
                                                int* __restrict__ rowptr) {
  __shared__ int s_w;
  const int tid = threadIdx.x;
  const int lane = tid & 63, wid = tid >> 6;
  int v = (tid < NSCANB) ? bsum[tid] : 0;
  int x = v;
#pragma unroll
  for (int off = 1; off < 64; off <<= 1) {
    int t = __shfl_up(x, off);
    if (lane >= off) x += t;
  }
  if (wid == 0 && lane == 63) s_w = x;
  __syncthreads();
  int incl = x + (wid == 1 ? s_w : 0);
  if (tid < NSCANB) bsum[tid] = incl - v;
  if (tid == NSCANB - 1) rowptr[N_NODES] = incl;
}

// ---------------- scan phase C ----------------
__global__ __launch_bounds__(1024) void k_scan_c(int* __restrict__ rowptr,
                                                 const int* __restrict__ bsum,
                                                 int* __restrict__ gcursor) {
  const int i = blockIdx.x * 1024 + threadIdx.x;
  if (i < N_NODES) {
    int r = rowptr[i] + bsum[blockIdx.x];
    rowptr[i] = r;
    if ((i & 511) == 0) gcursor[i >> 9] = r;
  }
}

// ---------------- bin graph edges by dst bucket ----------------
__global__ __launch_bounds__(256) void k_bin(const int* __restrict__ src,
                                             const int* __restrict__ dst,
                                             int* __restrict__ gcursor,
                                             int* __restrict__ binned) {
  __shared__ int hist[NBUCK];
  __shared__ int base[NBUCK];
  const int tid = threadIdx.x;
  const int e0 = blockIdx.x * 4096 + tid;
  for (int t = tid; t < NBUCK; t += 256) hist[t] = 0;
  __syncthreads();

  int w[16], bk[16], rk[16];
#pragma unroll
  for (int i = 0; i < 16; ++i) {
    int e = e0 + i * 256;
    if (e < N_EDGES) {
      int s = src[e], d = dst[e];
      bk[i] = d >> 9;
      w[i] = (s << 9) | (d & 511);
      rk[i] = atomicAdd(&hist[bk[i]], 1);
    } else {
      bk[i] = -1;
    }
  }
  __syncthreads();
  for (int t = tid; t < NBUCK; t += 256)
    base[t] = hist[t] > 0 ? atomicAdd(&gcursor[t], hist[t]) : 0;
  __syncthreads();
#pragma unroll
  for (int i = 0; i < 16; ++i)
    if (bk[i] >= 0) binned[base[bk[i]] + rk[i]] = w[i];
}

// ---------------- CSR fill from binned edges ----------------
__global__ __launch_bounds__(256) void k_fill2(const int* __restrict__ rowptr,
                                               const int* __restrict__ binned,
                                               int* __restrict__ csr) {
  __shared__ int lcur[512];
  const int b = blockIdx.x;
  const int nb = b << 9;
  const int nn = min(512, N_NODES - nb);
  for (int i = threadIdx.x; i < nn; i += 256) lcur[i] = rowptr[nb + i];
  __syncthreads();
  const int beg = rowptr[nb], end = rowptr[nb + nn];
  for (int e = beg + threadIdx.x; e < end; e += 256) {
    int w = binned[e];
    int pos = atomicAdd(&lcur[w & 511], 1);
    csr[pos] = w >> 9;
  }
}

// ---------------- bin label edges by src bucket (fixed-capacity regions) ----------------
// record: {d, (e<<9)|(s&511)} at lbin[bucket*LCAP + pos]; lblcnt = per-bucket count.
__global__ __launch_bounds__(256) void k_lbl_bin(const int* __restrict__ ls,
                                                 const int* __restrict__ ld,
                                                 int* __restrict__ lblcnt,
                                                 int2* __restrict__ lbin) {
  __shared__ int hist[NBUCK];
  __shared__ int base[NBUCK];
  const int tid = threadIdx.x;
  const int e0 = blockIdx.x * 4096 + tid;
  for (int t = tid; t < NBUCK; t += 256) hist[t] = 0;
  __syncthreads();

  int dd[16], pk[16], bk[16], rk[16];
#pragma unroll
  for (int i = 0; i < 16; ++i) {
    int e = e0 + i * 256;
    if (e < N_LBL) {
      int s = ls[e];
      dd[i] = ld[e];
      bk[i] = s >> 9;
      pk[i] = (e << 9) | (s & 511);
      rk[i] = atomicAdd(&hist[bk[i]], 1);
    } else {
      bk[i] = -1;
    }
  }
  __syncthreads();
  for (int t = tid; t < NBUCK; t += 256)
    base[t] = hist[t] > 0 ? atomicAdd(&lblcnt[t], hist[t]) : 0;
  __syncthreads();
#pragma unroll
  for (int i = 0; i < 16; ++i)
    if (bk[i] >= 0) {
      int2 rec = {dd[i], pk[i]};
      lbin[(long)bk[i] * LCAP + base[bk[i]] + rk[i]] = rec;
    }
}

// ---------------- prep: x -> bf16; all weights -> bf16 transposed [n][k] ----------------
__global__ __launch_bounds__(256) void k_prep(
    const float* __restrict__ x, const float* __restrict__ w1l,
    const float* __restrict__ w1r, const float* __restrict__ w2l,
    const float* __restrict__ w2r, const float* __restrict__ dw1,
    unsigned short* __restrict__ x16, unsigned short* __restrict__ w1lt,
    unsigned short* __restrict__ w1rt, unsigned short* __restrict__ w2lt,
    unsigned short* __restrict__ w2rt, unsigned short* __restrict__ dw1t) {
  long gid = (long)blockIdx.x * 256 + threadIdx.x;
  if (gid < 1600000) {
    long i = gid * 4;
    float4 v = *(const float4*)&x[i];
    ushort4 q = {f2bf(v.x), f2bf(v.y), f2bf(v.z), f2bf(v.w)};
    *(ushort4*)&x16[i] = q;
    return;
  }
  long idx = gid - 1600000;
  if (idx < 8192) { int n = idx >> 6, k = idx & 63; w1lt[idx] = f2bf(w1l[k * 128 + n]); return; }
  idx -= 8192;
  if (idx < 8192) { int n = idx >> 6, k = idx & 63; w1rt[idx] = f2bf(w1r[k * 128 + n]); return; }
  idx -= 8192;
  if (idx < 16384) { int n = idx >> 7, k = idx & 127; w2lt[idx] = f2bf(w2l[k * 128 + n]); return; }
  idx -= 16384;
  if (idx < 16384) { int n = idx >> 7, k = idx & 127; w2rt[idx] = f2bf(w2r[k * 128 + n]); return; }
  idx -= 16384;
  if (idx < 32768) {
    int n = idx >> 7, k = idx & 127;
    dw1t[idx] = f2bf(n < 128 ? dw1[k * 128 + n] : dw1[(k + 128) * 128 + (n - 128)]);
  }
}

// ---------------- gather aggregation D=64 (bf16 in/out) ----------------
__global__ __launch_bounds__(256) void k_agg64(const int* __restrict__ rowptr,
                                               const int* __restrict__ csr,
                                               const unsigned short* __restrict__ f16,
                                               const float* __restrict__ inv,
                                               unsigned short* __restrict__ out16) {
  const int lane = threadIdx.x & 63;
  const int n = blockIdx.x * 4 + (threadIdx.x >> 6);
  const int beg = rowptr[n], end = rowptr[n + 1];
  float acc = 0.0f;
  int j = beg;
  for (; j + 4 <= end; j += 4) {
    int s0 = csr[j], s1 = csr[j + 1], s2 = csr[j + 2], s3 = csr[j + 3];
    float f0 = bf_lo((unsigned int)f16[(long)s0 * 64 + lane]);
    float f1 = bf_lo((unsigned int)f16[(long)s1 * 64 + lane]);
    float f2 = bf_lo((unsigned int)f16[(long)s2 * 64 + lane]);
    float f3 = bf_lo((unsigned int)f16[(long)s3 * 64 + lane]);
    acc += f0; acc += f1; acc += f2; acc += f3;
  }
  for (; j < end; ++j) acc += bf_lo((unsigned int)f16[(long)csr[j] * 64 + lane]);
  out16[(long)n * 64 + lane] = f2bf(acc * inv[n]);
}

// ---------------- gather aggregation D=128 (bf16 in/out) ----------------
__global__ __launch_bounds__(256) void k_agg128(const int* __restrict__ rowptr,
                                                const int* __restrict__ csr,
                                                const unsigned short* __restrict__ f16,
                                                const float* __restrict__ inv,
                                                unsigned short* __restrict__ out16) {
  const int lane = threadIdx.x & 63;
  const int n = blockIdx.x * 4 + (threadIdx.x >> 6);
  const int beg = rowptr[n], end = rowptr[n + 1];
  float ax = 0.0f, ay = 0.0f;
  int j = beg;
  for (; j + 4 <= end; j += 4) {
    int s0 = csr[j], s1 = csr[j + 1], s2 = csr[j + 2], s3 = csr[j + 3];
    unsigned int w0 = *(const unsigned int*)&f16[(long)s0 * 128 + lane * 2];
    unsigned int w1 = *(const unsigned int*)&f16[(long)s1 * 128 + lane * 2];
    unsigned int w2 = *(const unsigned int*)&f16[(long)s2 * 128 + lane * 2];
    unsigned int w3 = *(const unsigned int*)&f16[(long)s3 * 128 + lane * 2];
    ax += bf_lo(w0); ay += bf_hi(w0);
    ax += bf_lo(w1); ay += bf_hi(w1);
    ax += bf_lo(w2); ay += bf_hi(w2);
    ax += bf_lo(w3); ay += bf_hi(w3);
  }
  for (; j < end; ++j) {
    unsigned int w = *(const unsigned int*)&f16[(long)csr[j] * 128 + lane * 2];
    ax += bf_lo(w); ay += bf_hi(w);
  }
  float iv = inv[n];
  unsigned int packed = ((unsigned int)f2bf(ay * iv) << 16) | f2bf(ax * iv);
  *(unsigned int*)&out16[(long)n * 128 + lane * 2] = packed;
}

// ---------------- MFMA layer 1 ----------------
__global__ __launch_bounds__(256) void k_l1(
    const unsigned short* __restrict__ m1, const unsigned short* __restrict__ x16,
    const unsigned short* __restrict__ w1lt, const unsigned short* __restrict__ w1rt,
    const float* __restrict__ b1l, unsigned short* __restrict__ h16) {
  const int l = threadIdx.x & 63;
  const int w = threadIdx.x >> 6;
  const int cl = l & 15;
  const int kh = l >> 4;
  const int wrow0 = blockIdx.x * 128 + w * 32;
  int ar0 = wrow0 + cl;      if (ar0 >= N_NODES) ar0 = N_NODES - 1;
  int ar1 = wrow0 + 16 + cl; if (ar1 >= N_NODES) ar1 = N_NODES - 1;

  f32x4 acc[2][8];
#pragma unroll
  for (int t = 0; t < 2; ++t)
#pragma unroll
    for (int nt = 0; nt < 8; ++nt) acc[t][nt] = (f32x4){0.f, 0.f, 0.f, 0.f};

#pragma unroll
  for (int s = 0; s < 2; ++s) {
    const int ko = s * 32 + kh * 8;
    bf16x8 am0 = *(const bf16x8*)(m1 + (long)ar0 * 64 + ko);
    bf16x8 ax0 = *(const bf16x8*)(x16 + (long)ar0 * 64 + ko);
    bf16x8 am1 = *(const bf16x8*)(m1 + (long)ar1 * 64 + ko);
    bf16x8 ax1 = *(const bf16x8*)(x16 + (long)ar1 * 64 + ko);
#pragma unroll
    for (int nt = 0; nt < 8; ++nt) {
      bf16x8 bl = *(const bf16x8*)(w1lt + (long)(nt * 16 + cl) * 64 + ko);
      bf16x8 br = *(const bf16x8*)(w1rt + (long)(nt * 16 + cl) * 64 + ko);
      acc[0][nt] = __builtin_amdgcn_mfma_f32_16x16x32_bf16(am0, bl, acc[0][nt], 0, 0, 0);
      acc[0][nt] = __builtin_amdgcn_mfma_f32_16x16x32_bf16(ax0, br, acc[0][nt], 0, 0, 0);
      acc[1][nt] = __builtin_amdgcn_mfma_f32_16x16x32_bf16(am1, bl, acc[1][nt], 0, 0, 0);
      acc[1][nt] = __builtin_amdgcn_mfma_f32_16x16x32_bf16(ax1, br, acc[1][nt], 0, 0, 0);
    }
  }

#pragma unroll
  for (int t = 0; t < 2; ++t)
#pragma unroll
    for (int nt = 0; nt < 8; ++nt) {
      float b = b1l[nt * 16 + cl];
#pragma unroll
      for (int i = 0; i < 4; ++i) {
        int r = wrow0 + t * 16 + kh * 4 + i;
        if (r < N_NODES)
          h16[(long)r * 128 + nt * 16 + cl] = f2bf(fmaxf(acc[t][nt][i] + b, 0.0f));
      }
    }
}

// ---------------- MFMA fused layer 2 + u/v (db1 folded into u16) ----------------
__global__ __launch_bounds__(256) void k_l2uv(
    const unsigned short* __restrict__ m2, const unsigned short* __restrict__ h16,
    const unsigned short* __restrict__ w2lt, const unsigned short* __restrict__ w2rt,
    const float* __restrict__ b2l, const unsigned short* __restrict__ dw1t,
    const float* __restrict__ db1,
    unsigned short* __restrict__ u16, unsigned short* __restrict__ v16) {
  __shared__ unsigned short s_z[128 * 128];  // 32 KB, XOR-swizzled rows
  char* zb = (char*)s_z;
  const int l = threadIdx.x & 63;
  const int w = threadIdx.x >> 6;
  const int cl = l & 15;
  const int kh = l >> 4;
  const int wrow0 = blockIdx.x * 128 + w * 32;
  int ar0 = wrow0 + cl;      if (ar0 >= N_NODES) ar0 = N_NODES - 1;
  int ar1 = wrow0 + 16 + cl; if (ar1 >= N_NODES) ar1 = N_NODES - 1;

  f32x4 acc[2][8];
#pragma unroll
  for (int t = 0; t < 2; ++t)
#pragma unroll
    for (int nt = 0; nt < 8; ++nt) acc[t][nt] = (f32x4){0.f, 0.f, 0.f, 0.f};

#pragma unroll
  for (int s = 0; s < 4; ++s) {
    const int ko = s * 32 + kh * 8;
    bf16x8 am0 = *(const bf16x8*)(m2 + (long)ar0 * 128 + ko);
    bf16x8 ah0 = *(const bf16x8*)(h16 + (long)ar0 * 128 + ko);
    bf16x8 am1 = *(const bf16x8*)(m2 + (long)ar1 * 128 + ko);
    bf16x8 ah1 = *(const bf16x8*)(h16 + (long)ar1 * 128 + ko);
#pragma unroll
    for (int nt = 0; nt < 8; ++nt) {
      bf16x8 bl = *(const bf16x8*)(w2lt + (long)(nt * 16 + cl) * 128 + ko);
      bf16x8 br = *(const bf16x8*)(w2rt + (long)(nt * 16 + cl) * 128 + ko);
      acc[0][nt] = __builtin_amdgcn_mfma_f32_16x16x32_bf16(am0, bl, acc[0][nt], 0, 0, 0);
      acc[0][nt] = __builtin_amdgcn_mfma_f32_16x16x32_bf16(ah0, br, acc[0][nt], 0, 0, 0);
      acc[1][nt] = __builtin_amdgcn_mfma_f32_16x16x32_bf16(am1, bl, acc[1][nt], 0, 0, 0);
      acc[1][nt] = __builtin_amdgcn_mfma_f32_16x16x32_bf16(ah1, br, acc[1][nt], 0, 0, 0);
    }
  }

#pragma unroll
  for (int t = 0; t < 2; ++t)
#pragma unroll
    for (int nt = 0; nt < 8; ++nt) {
      float b = b2l[nt * 16 + cl];
#pragma unroll
      for (int i = 0; i < 4; ++i) {
        int zr = w * 32 + t * 16 + kh * 4 + i;
        int byte = (zr * 256 + (nt * 16 + cl) * 2) ^ ((zr & 7) << 4);
        *(unsigned short*)(zb + byte) = f2bf(acc[t][nt][i] + b);
      }
    }
  __syncthreads();

  // ---- pass u (adds db1) ----
  f32x4 uu[2][8];
#pragma unroll
  for (int t = 0; t < 2; ++t)
#pragma unroll
    for (int nt = 0; nt < 8; ++nt) uu[t][nt] = (f32x4){0.f, 0.f, 0.f, 0.f};
#pragma unroll
  for (int s = 0; s < 4; ++s) {
    const int zr0 = w * 32 + cl;
    const int zr1 = w * 32 + 16 + cl;
    bf16x8 az0 = *(const bf16x8*)(zb + ((zr0 * 256 + s * 64 + kh * 16) ^ ((zr0 & 7) << 4)));
    bf16x8 az1 = *(const bf16x8*)(zb + ((zr1 * 256 + s * 64 + kh * 16) ^ ((zr1 & 7) << 4)));
#pragma unroll
    for (int nt = 0; nt < 8; ++nt) {
      bf16x8 bu = *(const bf16x8*)(dw1t + (long)(nt * 16 + cl) * 128 + s * 32 + kh * 8);
      uu[0][nt] = __builtin_amdgcn_mfma_f32_16x16x32_bf16(az0, bu, uu[0][nt], 0, 0, 0);
      uu[1][nt] = __builtin_amdgcn_mfma_f32_16x16x32_bf16(az1, bu, uu[1][nt], 0, 0, 0);
    }
  }
#pragma unroll
  for (int t = 0; t < 2; ++t)
#pragma unroll
    for (int nt = 0; nt < 8; ++nt) {
      float bb = db1[nt * 16 + cl];
#pragma unroll
      for (int i = 0; i < 4; ++i) {
        int r = wrow0 + t * 16 + kh * 4 + i;
        if (r < N_NODES) u16[(long)r * 128 + nt * 16 + cl] = f2bf(uu[t][nt][i] + bb);
      }
    }

  // ---- pass v ----
#pragma unroll
  for (int t = 0; t < 2; ++t)
#pragma unroll
    for (int nt = 0; nt < 8; ++nt) uu[t][nt] = (f32x4){0.f, 0.f, 0.f, 0.f};
#pragma unroll
  for (int s = 0; s < 4; ++s) {
    const int zr0 = w * 32 + cl;
    const int zr1 = w * 32 + 16 + cl;
    bf16x8 az0 = *(const bf16x8*)(zb + ((zr0 * 256 + s * 64 + kh * 16) ^ ((zr0 & 7) << 4)));
    bf16x8 az1 = *(const bf16x8*)(zb + ((zr1 * 256 + s * 64 + kh * 16) ^ ((zr1 & 7) << 4)));
#pragma unroll
    for (int nt = 0; nt < 8; ++nt) {
      bf16x8 bv = *(const bf16x8*)(dw1t + (long)((nt + 8) * 16 + cl) * 128 + s * 32 + kh * 8);
      uu[0][nt] = __builtin_amdgcn_mfma_f32_16x16x32_bf16(az0, bv, uu[0][nt], 0, 0, 0);
      uu[1][nt] = __builtin_amdgcn_mfma_f32_16x16x32_bf16(az1, bv, uu[1][nt], 0, 0, 0);
    }
  }
#pragma unroll
  for (int t = 0; t < 2; ++t)
#pragma unroll
    for (int nt = 0; nt < 8; ++nt)
#pragma unroll
      for (int i = 0; i < 4; ++i) {
        int r = wrow0 + t * 16 + kh * 4 + i;
        if (r < N_NODES) v16[(long)r * 128 + nt * 16 + cl] = f2bf(uu[t][nt][i]);
      }
}

// ---------------- per-label-edge decoder: bucketed, 16 lanes/edge ----------------
// u already includes db1. out = relu(u[s]+v[d])·dw2 + db2.
__global__ __launch_bounds__(256) void k_edge2(
    const int* __restrict__ lblcnt, const int2* __restrict__ lbin,
    const unsigned short* __restrict__ u16, const unsigned short* __restrict__ v16,
    const float* __restrict__ dw2, const float* __restrict__ db2,
    float* __restrict__ out) {
  const int lane = threadIdx.x & 63;
  const int wv = threadIdx.x >> 6;  // 0..3
  const int g = lane >> 4;          // edge slot within wave: 0..3
  const int q = lane & 15;
  const int b = blockIdx.x / (LCAP / 16);          // bucket
  const int chunk = blockIdx.x % (LCAP / 16);      // 192 chunks of 16 slots
  const int idx = chunk * 16 + wv * 4 + g;
  if (idx >= lblcnt[b]) return;
  int2 rec = lbin[(long)b * LCAP + idx];
  int d = rec.x;
  int s = (b << 9) + (rec.y & 511);
  int e = rec.y >> 9;

  bf16x8 uu = *(const bf16x8*)(u16 + (long)s * 128 + q * 8);
  bf16x8 vv = *(const bf16x8*)(v16 + (long)d * 128 + q * 8);
  float4 w0 = *(const float4*)&dw2[q * 8];
  float4 w1 = *(const float4*)&dw2[q * 8 + 4];
  float w8[8] = {w0.x, w0.y, w0.z, w0.w, w1.x, w1.y, w1.z, w1.w};
  float sum = 0.0f;
#pragma unroll
  for (int i = 0; i < 8; ++i) {
    float h = fmaxf(bfs(uu[i]) + bfs(vv[i]), 0.0f);
    sum = fmaf(h, w8[i], sum);
  }
  sum += __shfl_xor(sum, 1);
  sum += __shfl_xor(sum, 2);
  sum += __shfl_xor(sum, 4);
  sum += __shfl_xor(sum, 8);
  if (q == 0) out[e] = sum + db2[0];
}

extern "C" void kernel_launch(void* const* d_in, const int* in_sizes, int n_in,
                              void* d_out, int out_size, void* d_ws, size_t ws_size,
                              hipStream_t stream) {
  const float* x   = (const float*)d_in[0];
  const int*   ei  = (const int*)d_in[1];
  const int*   eli = (const int*)d_in[2];
  const float* w1l = (const float*)d_in[3];
  const float* b1l = (const float*)d_in[4];
  const float* w1r = (const float*)d_in[5];
  const float* w2l = (const float*)d_in[6];
  const float* b2l = (const float*)d_in[7];
  const float* w2r = (const float*)d_in[8];
  const float* dw1 = (const float*)d_in[9];
  const float* db1 = (const float*)d_in[10];
  const float* dw2 = (const float*)d_in[11];
  const float* db2 = (const float*)d_in[12];
  float* out = (float*)d_out;

  // ---- workspace layout (byte offsets, 16B aligned) ----
  char* wsb = (char*)d_ws;
  float* inv     = (float*)(wsb + 0);              // 400000
  int*   deg_i   = (int*)(wsb + 400000);           // 400000
  int*   rowptr  = (int*)(wsb + 800000);           // 400032
  int*   gcursor = (int*)(wsb + 1200032);          // 1024
  int*   csr     = (int*)(wsb + 1201056);          // 6400000
  int*   binned  = (int*)(wsb + 7601056);          // 6400000
  unsigned short* x16  = (unsigned short*)(wsb + 14001056);   // 12.8 MB
  unsigned short* m1   = (unsigned short*)(wsb + 26801056);   // 12.8 MB
  unsigned short* u16  = (unsigned short*)(wsb + 14001056);   // 25.6 MB (aliases x16+m1)
  unsigned short* h16  = (unsigned short*)(wsb + 39601056);   // 25.6 MB
  unsigned short* m2   = (unsigned short*)(wsb + 65201056);   // 25.6 MB
  unsigned short* v16  = (unsigned short*)(wsb + 90801056);   // 25.6 MB
  unsigned short* w1lt = (unsigned short*)(wsb + 116401056);  // 16384
  unsigned short* w1rt = (unsigned short*)(wsb + 116417440);  // 16384
  unsigned short* w2lt = (unsigned short*)(wsb + 116433824);  // 32768
  unsigned short* w2rt = (unsigned short*)(wsb + 116466592);  // 32768
  unsigned short* dw1t = (unsigned short*)(wsb + 116499360);  // 65536
  int*   bsum    = (int*)(wsb + 116564896);        // 512
  int*   lblcnt  = (int*)(wsb + 116565408);        // 800 (196 used, pad)
  int2*  lbin    = (int2*)(wsb + 116566208);       // 196*3072*8 = 4816896 -> ends ~121.4 MB

  const int* srcp = ei;
  const int* dstp = ei + N_EDGES;
  const int* lsp  = eli;
  const int* ldp  = eli + N_LBL;

  // ---- CSR build + label-edge binning + prep ----
  hipMemsetAsync(deg_i, 0, N_NODES * sizeof(int), stream);
  hipMemsetAsync(lblcnt, 0, NBUCK * sizeof(int), stream);
  k_deg<<<N_EDGES / 256, 256, 0, stream>>>(dstp, deg_i);
  k_scan_a<<<NSCANB, 1024, 0, stream>>>(deg_i, rowptr, inv, bsum);
  k_scan_b<<<1, 128, 0, stream>>>(bsum, rowptr);
  k_scan_c<<<NSCANB, 1024, 0, stream>>>(rowptr, bsum, gcursor);
  k_bin<<<(N_EDGES + 4095) / 4096, 256, 0, stream>>>(srcp, dstp, gcursor, binned);
  k_fill2<<<NBUCK, 256, 0, stream>>>(rowptr, binned, csr);
  k_lbl_bin<<<(N_LBL + 4095) / 4096, 256, 0, stream>>>(lsp, ldp, lblcnt, lbin);
  k_prep<<<(1681920 + 255) / 256, 256, 0, stream>>>(
      x, w1l, w1r, w2l, w2r, dw1, x16, w1lt, w1rt, w2lt, w2rt, dw1t);

  // ---- layer 1 (MFMA) ----
  k_agg64<<<N_NODES / 4, 256, 0, stream>>>(rowptr, csr, x16, inv, m1);
  k_l1<<<(N_NODES + 127) / 128, 256, 0, stream>>>(m1, x16, w1lt, w1rt, b1l, h16);

  // ---- layer 2 + u/v (MFMA) ----
  k_agg128<<<N_NODES / 4, 256, 0, stream>>>(rowptr, csr, h16, inv, m2);
  k_l2uv<<<(N_NODES + 127) / 128, 256, 0, stream>>>(m2, h16, w2lt, w2rt, b2l, dw1t, db1, u16, v16);

  // ---- decoder edge MLP (bucketed) ----
  k_edge2<<<NBUCK * (LCAP / 16), 256, 0, stream>>>(lblcnt, lbin, u16, v16, dw2, db2, out);
}

// Round 14
// 446.482 us; speedup vs baseline: 2.1005x; 1.0167x over previous
//
#include <hip/hip_runtime.h>

#define N_NODES 100000
#define D_IN 64
#define HID 128
#define N_EDGES 1600000
#define N_LBL 500000
#define NBUCK 196   // ceil(100000/512) buckets of 512 dst nodes
#define NSCANB 98   // ceil(100000/1024) scan blocks
#define LCAP 3072   // label-edge bucket capacity (lambda=2560, sigma~51)

typedef __attribute__((ext_vector_type(8))) short bf16x8;
typedef __attribute__((ext_vector_type(4))) float f32x4;

// ---- bf16 helpers (RNE) ----
__device__ inline unsigned short f2bf(float f) {
  unsigned int u = __float_as_uint(f);
  return (unsigned short)((u + 0x7FFFu + ((u >> 16) & 1u)) >> 16);
}
__device__ inline float bf_lo(unsigned int w) { return __uint_as_float(w << 16); }
__device__ inline float bf_hi(unsigned int w) { return __uint_as_float(w & 0xFFFF0000u); }
__device__ inline float bfs(short s) {
  return __uint_as_float(((unsigned int)(unsigned short)s) << 16);
}

// ---------------- degree histogram (int) ----------------
__global__ __launch_bounds__(256) void k_deg(const int* __restrict__ dst,
                                             int* __restrict__ deg) {
  int e = blockIdx.x * 256 + threadIdx.x;
  if (e < N_EDGES) atomicAdd(&deg[dst[e]], 1);
}

// ---------------- scan phase A ----------------
__global__ __launch_bounds__(1024) void k_scan_a(const int* __restrict__ deg,
                                                 int* __restrict__ rowptr,
                                                 float* __restrict__ inv,
                                                 int* __restrict__ bsum) {
  __shared__ int s_wsum[16];
  const int lane = threadIdx.x & 63;
  const int wid = threadIdx.x >> 6;
  const int i = blockIdx.x * 1024 + threadIdx.x;
  int v = (i < N_NODES) ? deg[i] : 0;
  int x = v;
#pragma unroll
  for (int off = 1; off < 64; off <<= 1) {
    int t = __shfl_up(x, off);
    if (lane >= off) x += t;
  }
  if (lane == 63) s_wsum[wid] = x;
  __syncthreads();
  if (wid == 0 && lane < 16) {
    int ws = s_wsum[lane];
    int y = ws;
#pragma unroll
    for (int off = 1; off < 16; off <<= 1) {
      int t = __shfl_up(y, off);
      if (lane >= off) y += t;
    }
    s_wsum[lane] = y - ws;
    if (lane == 15) bsum[blockIdx.x] = y;
  }
  __syncthreads();
  if (i < N_NODES) {
    rowptr[i] = s_wsum[wid] + x - v;
    inv[i] = v > 0 ? 1.0f / (float)v : 0.0f;
  }
}

// ---------------- scan phase B ----------------
__global__ __launch_bounds__(128) void k_scan_b(int* __restrict__ bsum,
                                                int* __restrict__ rowptr) {
  __shared__ int s_w;
  const int tid = threadIdx.x;
  const int lane = tid & 63, wid = tid >> 6;
  int v = (tid < NSCANB) ? bsum[tid] : 0;
  int x = v;
#pragma unroll
  for (int off = 1; off < 64; off <<= 1) {
    int t = __shfl_up(x, off);
    if (lane >= off) x += t;
  }
  if (wid == 0 && lane == 63) s_w = x;
  __syncthreads();
  int incl = x + (wid == 1 ? s_w : 0);
  if (tid < NSCANB) bsum[tid] = incl - v;
  if (tid == NSCANB - 1) rowptr[N_NODES] = incl;
}

// ---------------- scan phase C ----------------
__global__ __launch_bounds__(1024) void k_scan_c(int* __restrict__ rowptr,
                                                 const int* __restrict__ bsum,
                                                 int* __restrict__ gcursor) {
  const int i = blockIdx.x * 1024 + threadIdx.x;
  if (i < N_NODES) {
    int r = rowptr[i] + bsum[blockIdx.x];
    rowptr[i] = r;
    if ((i & 511) == 0) gcursor[i >> 9] = r;
  }
}

// ---------------- bin graph edges by dst bucket ----------------
__global__ __launch_bounds__(256) void k_bin(const int* __restrict__ src,
                                             const int* __restrict__ dst,
                                             int* __restrict__ gcursor,
                                             int* __restrict__ binned) {
  __shared__ int hist[NBUCK];
  __shared__ int base[NBUCK];
  const int tid = threadIdx.x;
  const int e0 = blockIdx.x * 4096 + tid;
  for (int t = tid; t < NBUCK; t += 256) hist[t] = 0;
  __syncthreads();

  int w[16], bk[16], rk[16];
#pragma unroll
  for (int i = 0; i < 16; ++i) {
    int e = e0 + i * 256;
    if (e < N_EDGES) {
      int s = src[e], d = dst[e];
      bk[i] = d >> 9;
      w[i] = (s << 9) | (d & 511);
      rk[i] = atomicAdd(&hist[bk[i]], 1);
    } else {
      bk[i] = -1;
    }
  }
  __syncthreads();
  for (int t = tid; t < NBUCK; t += 256)
    base[t] = hist[t] > 0 ? atomicAdd(&gcursor[t], hist[t]) : 0;
  __syncthreads();
#pragma unroll
  for (int i = 0; i < 16; ++i)
    if (bk[i] >= 0) binned[base[bk[i]] + rk[i]] = w[i];
}

// ---------------- CSR fill from binned edges ----------------
__global__ __launch_bounds__(256) void k_fill2(const int* __restrict__ rowptr,
                                               const int* __restrict__ binned,
                                               int* __restrict__ csr) {
  __shared__ int lcur[512];
  const int b = blockIdx.x;
  const int nb = b << 9;
  const int nn = min(512, N_NODES - nb);
  for (int i = threadIdx.x; i < nn; i += 256) lcur[i] = rowptr[nb + i];
  __syncthreads();
  const int beg = rowptr[nb], end = rowptr[nb + nn];
  for (int e = beg + threadIdx.x; e < end; e += 256) {
    int w = binned[e];
    int pos = atomicAdd(&lcur[w & 511], 1);
    csr[pos] = w >> 9;
  }
}

// ---------------- bin label edges by src bucket (fixed-capacity regions) ----------------
__global__ __launch_bounds__(256) void k_lbl_bin(const int* __restrict__ ls,
                                                 const int* __restrict__ ld,
                                                 int* __restrict__ lblcnt,
                                                 int2* __restrict__ lbin) {
  __shared__ int hist[NBUCK];
  __shared__ int base[NBUCK];
  const int tid = threadIdx.x;
  const int e0 = blockIdx.x * 4096 + tid;
  for (int t = tid; t < NBUCK; t += 256) hist[t] = 0;
  __syncthreads();

  int dd[16], pk[16], bk[16], rk[16];
#pragma unroll
  for (int i = 0; i < 16; ++i) {
    int e = e0 + i * 256;
    if (e < N_LBL) {
      int s = ls[e];
      dd[i] = ld[e];
      bk[i] = s >> 9;
      pk[i] = (e << 9) | (s & 511);
      rk[i] = atomicAdd(&hist[bk[i]], 1);
    } else {
      bk[i] = -1;
    }
  }
  __syncthreads();
  for (int t = tid; t < NBUCK; t += 256)
    base[t] = hist[t] > 0 ? atomicAdd(&lblcnt[t], hist[t]) : 0;
  __syncthreads();
#pragma unroll
  for (int i = 0; i < 16; ++i)
    if (bk[i] >= 0) {
      int2 rec = {dd[i], pk[i]};
      lbin[(long)bk[i] * LCAP + base[bk[i]] + rk[i]] = rec;
    }
}

// ---------------- prep: x -> bf16; all weights -> bf16 transposed [n][k] ----------------
__global__ __launch_bounds__(256) void k_prep(
    const float* __restrict__ x, const float* __restrict__ w1l,
    const float* __restrict__ w1r, const float* __restrict__ w2l,
    const float* __restrict__ w2r, const float* __restrict__ dw1,
    unsigned short* __restrict__ x16, unsigned short* __restrict__ w1lt,
    unsigned short* __restrict__ w1rt, unsigned short* __restrict__ w2lt,
    unsigned short* __restrict__ w2rt, unsigned short* __restrict__ dw1t) {
  long gid = (long)blockIdx.x * 256 + threadIdx.x;
  if (gid < 1600000) {
    long i = gid * 4;
    float4 v = *(const float4*)&x[i];
    ushort4 q = {f2bf(v.x), f2bf(v.y), f2bf(v.z), f2bf(v.w)};
    *(ushort4*)&x16[i] = q;
    return;
  }
  long idx = gid - 1600000;
  if (idx < 8192) { int n = idx >> 6, k = idx & 63; w1lt[idx] = f2bf(w1l[k * 128 + n]); return; }
  idx -= 8192;
  if (idx < 8192) { int n = idx >> 6, k = idx & 63; w1rt[idx] = f2bf(w1r[k * 128 + n]); return; }
  idx -= 8192;
  if (idx < 16384) { int n = idx >> 7, k = idx & 127; w2lt[idx] = f2bf(w2l[k * 128 + n]); return; }
  idx -= 16384;
  if (idx < 16384) { int n = idx >> 7, k = idx & 127; w2rt[idx] = f2bf(w2r[k * 128 + n]); return; }
  idx -= 16384;
  if (idx < 32768) {
    int n = idx >> 7, k = idx & 127;
    dw1t[idx] = f2bf(n < 128 ? dw1[k * 128 + n] : dw1[(k + 128) * 128 + (n - 128)]);
  }
}

// ---------------- gather aggregation D=64 (bf16 in/out) ----------------
__global__ __launch_bounds__(256) void k_agg64(const int* __restrict__ rowptr,
                                               const int* __restrict__ csr,
                                               const unsigned short* __restrict__ f16,
                                               const float* __restrict__ inv,
                                               unsigned short* __restrict__ out16) {
  const int lane = threadIdx.x & 63;
  const int n = blockIdx.x * 4 + (threadIdx.x >> 6);
  const int beg = rowptr[n], end = rowptr[n + 1];
  float acc = 0.0f;
  int j = beg;
  for (; j + 4 <= end; j += 4) {
    int s0 = csr[j], s1 = csr[j + 1], s2 = csr[j + 2], s3 = csr[j + 3];
    float f0 = bf_lo((unsigned int)f16[(long)s0 * 64 + lane]);
    float f1 = bf_lo((unsigned int)f16[(long)s1 * 64 + lane]);
    float f2 = bf_lo((unsigned int)f16[(long)s2 * 64 + lane]);
    float f3 = bf_lo((unsigned int)f16[(long)s3 * 64 + lane]);
    acc += f0; acc += f1; acc += f2; acc += f3;
  }
  for (; j < end; ++j) acc += bf_lo((unsigned int)f16[(long)csr[j] * 64 + lane]);
  out16[(long)n * 64 + lane] = f2bf(acc * inv[n]);
}

// ---------------- gather aggregation D=128 (bf16 in/out) ----------------
__global__ __launch_bounds__(256) void k_agg128(const int* __restrict__ rowptr,
                                                const int* __restrict__ csr,
                                                const unsigned short* __restrict__ f16,
                                                const float* __restrict__ inv,
                                                unsigned short* __restrict__ out16) {
  const int lane = threadIdx.x & 63;
  const int n = blockIdx.x * 4 + (threadIdx.x >> 6);
  const int beg = rowptr[n], end = rowptr[n + 1];
  float ax = 0.0f, ay = 0.0f;
  int j = beg;
  for (; j + 4 <= end; j += 4) {
    int s0 = csr[j], s1 = csr[j + 1], s2 = csr[j + 2], s3 = csr[j + 3];
    unsigned int w0 = *(const unsigned int*)&f16[(long)s0 * 128 + lane * 2];
    unsigned int w1 = *(const unsigned int*)&f16[(long)s1 * 128 + lane * 2];
    unsigned int w2 = *(const unsigned int*)&f16[(long)s2 * 128 + lane * 2];
    unsigned int w3 = *(const unsigned int*)&f16[(long)s3 * 128 + lane * 2];
    ax += bf_lo(w0); ay += bf_hi(w0);
    ax += bf_lo(w1); ay += bf_hi(w1);
    ax += bf_lo(w2); ay += bf_hi(w2);
    ax += bf_lo(w3); ay += bf_hi(w3);
  }
  for (; j < end; ++j) {
    unsigned int w = *(const unsigned int*)&f16[(long)csr[j] * 128 + lane * 2];
    ax += bf_lo(w); ay += bf_hi(w);
  }
  float iv = inv[n];
  unsigned int packed = ((unsigned int)f2bf(ay * iv) << 16) | f2bf(ax * iv);
  *(unsigned int*)&out16[(long)n * 128 + lane * 2] = packed;
}

// ---------------- MFMA layer 1 ----------------
__global__ __launch_bounds__(256) void k_l1(
    const unsigned short* __restrict__ m1, const unsigned short* __restrict__ x16,
    const unsigned short* __restrict__ w1lt, const unsigned short* __restrict__ w1rt,
    const float* __restrict__ b1l, unsigned short* __restrict__ h16) {
  const int l = threadIdx.x & 63;
  const int w = threadIdx.x >> 6;
  const int cl = l & 15;
  const int kh = l >> 4;
  const int wrow0 = blockIdx.x * 128 + w * 32;
  int ar0 = wrow0 + cl;      if (ar0 >= N_NODES) ar0 = N_NODES - 1;
  int ar1 = wrow0 + 16 + cl; if (ar1 >= N_NODES) ar1 = N_NODES - 1;

  f32x4 acc[2][8];
#pragma unroll
  for (int t = 0; t < 2; ++t)
#pragma unroll
    for (int nt = 0; nt < 8; ++nt) acc[t][nt] = (f32x4){0.f, 0.f, 0.f, 0.f};

#pragma unroll
  for (int s = 0; s < 2; ++s) {
    const int ko = s * 32 + kh * 8;
    bf16x8 am0 = *(const bf16x8*)(m1 + (long)ar0 * 64 + ko);
    bf16x8 ax0 = *(const bf16x8*)(x16 + (long)ar0 * 64 + ko);
    bf16x8 am1 = *(const bf16x8*)(m1 + (long)ar1 * 64 + ko);
    bf16x8 ax1 = *(const bf16x8*)(x16 + (long)ar1 * 64 + ko);
#pragma unroll
    for (int nt = 0; nt < 8; ++nt) {
      bf16x8 bl = *(const bf16x8*)(w1lt + (long)(nt * 16 + cl) * 64 + ko);
      bf16x8 br = *(const bf16x8*)(w1rt + (long)(nt * 16 + cl) * 64 + ko);
      acc[0][nt] = __builtin_amdgcn_mfma_f32_16x16x32_bf16(am0, bl, acc[0][nt], 0, 0, 0);
      acc[0][nt] = __builtin_amdgcn_mfma_f32_16x16x32_bf16(ax0, br, acc[0][nt], 0, 0, 0);
      acc[1][nt] = __builtin_amdgcn_mfma_f32_16x16x32_bf16(am1, bl, acc[1][nt], 0, 0, 0);
      acc[1][nt] = __builtin_amdgcn_mfma_f32_16x16x32_bf16(ax1, br, acc[1][nt], 0, 0, 0);
    }
  }

#pragma unroll
  for (int t = 0; t < 2; ++t)
#pragma unroll
    for (int nt = 0; nt < 8; ++nt) {
      float b = b1l[nt * 16 + cl];
#pragma unroll
      for (int i = 0; i < 4; ++i) {
        int r = wrow0 + t * 16 + kh * 4 + i;
        if (r < N_NODES)
          h16[(long)r * 128 + nt * 16 + cl] = f2bf(fmaxf(acc[t][nt][i] + b, 0.0f));
      }
    }
}

// ---------------- MFMA fused layer 2 + u/v — BARRIER-FREE (wave-private z) ----------------
// Each wave computes all 128 cols of its own 32 rows, stashes z into its own
// 8 KB LDS region (XOR-swizzled), and reads back its own rows for the u/v
// passes. No __syncthreads: intra-wave LDS ordering via lgkmcnt only. Waves
// de-phase naturally -> memory latency of one wave overlaps MFMA of another.
// 128-thread blocks (2 waves), grid 1563.
__global__ __launch_bounds__(128) void k_l2uv(
    const unsigned short* __restrict__ m2, const unsigned short* __restrict__ h16,
    const unsigned short* __restrict__ w2lt, const unsigned short* __restrict__ w2rt,
    const float* __restrict__ b2l, const unsigned short* __restrict__ dw1t,
    const float* __restrict__ db1,
    unsigned short* __restrict__ u16, unsigned short* __restrict__ v16) {
  __shared__ unsigned short s_z[2][32 * 128];  // 16 KB: 8 KB per wave
  const int l = threadIdx.x & 63;
  const int w = threadIdx.x >> 6;  // wave 0/1
  char* zb = (char*)s_z[w];
  const int cl = l & 15;
  const int kh = l >> 4;
  const int wrow0 = blockIdx.x * 64 + w * 32;  // grid 1563, tail guarded
  int ar0 = wrow0 + cl;      if (ar0 >= N_NODES) ar0 = N_NODES - 1;
  int ar1 = wrow0 + 16 + cl; if (ar1 >= N_NODES) ar1 = N_NODES - 1;

  f32x4 acc[2][8];
#pragma unroll
  for (int t = 0; t < 2; ++t)
#pragma unroll
    for (int nt = 0; nt < 8; ++nt) acc[t][nt] = (f32x4){0.f, 0.f, 0.f, 0.f};

#pragma unroll
  for (int s = 0; s < 4; ++s) {
    const int ko = s * 32 + kh * 8;
    bf16x8 am0 = *(const bf16x8*)(m2 + (long)ar0 * 128 + ko);
    bf16x8 ah0 = *(const bf16x8*)(h16 + (long)ar0 * 128 + ko);
    bf16x8 am1 = *(const bf16x8*)(m2 + (long)ar1 * 128 + ko);
    bf16x8 ah1 = *(const bf16x8*)(h16 + (long)ar1 * 128 + ko);
#pragma unroll
    for (int nt = 0; nt < 8; ++nt) {
      bf16x8 bl = *(const bf16x8*)(w2lt + (long)(nt * 16 + cl) * 128 + ko);
      bf16x8 br = *(const bf16x8*)(w2rt + (long)(nt * 16 + cl) * 128 + ko);
      acc[0][nt] = __builtin_amdgcn_mfma_f32_16x16x32_bf16(am0, bl, acc[0][nt], 0, 0, 0);
      acc[0][nt] = __builtin_amdgcn_mfma_f32_16x16x32_bf16(ah0, br, acc[0][nt], 0, 0, 0);
      acc[1][nt] = __builtin_amdgcn_mfma_f32_16x16x32_bf16(am1, bl, acc[1][nt], 0, 0, 0);
      acc[1][nt] = __builtin_amdgcn_mfma_f32_16x16x32_bf16(ah1, br, acc[1][nt], 0, 0, 0);
    }
  }

  // z (+bias) -> wave-private LDS (local rows 0..31), swizzle byte ^= (row&7)<<4
#pragma unroll
  for (int t = 0; t < 2; ++t)
#pragma unroll
    for (int nt = 0; nt < 8; ++nt) {
      float b = b2l[nt * 16 + cl];
#pragma unroll
      for (int i = 0; i < 4; ++i) {
        int zr = t * 16 + kh * 4 + i;  // 0..31 local
        int byte = (zr * 256 + (nt * 16 + cl) * 2) ^ ((zr & 7) << 4);
        *(unsigned short*)(zb + byte) = f2bf(acc[t][nt][i] + b);
      }
    }
  // no __syncthreads: z region is wave-private; lgkmcnt orders write->read.

  // ---- pass u (adds db1) ----
  f32x4 uu[2][8];
#pragma unroll
  for (int t = 0; t < 2; ++t)
#pragma unroll
    for (int nt = 0; nt < 8; ++nt) uu[t][nt] = (f32x4){0.f, 0.f, 0.f, 0.f};
#pragma unroll
  for (int s = 0; s < 4; ++s) {
    const int zr0 = cl;        // local rows
    const int zr1 = 16 + cl;
    bf16x8 az0 = *(const bf16x8*)(zb + ((zr0 * 256 + s * 64 + kh * 16) ^ ((zr0 & 7) << 4)));
    bf16x8 az1 = *(const bf16x8*)(zb + ((zr1 * 256 + s * 64 + kh * 16) ^ ((zr1 & 7) << 4)));
#pragma unroll
    for (int nt = 0; nt < 8; ++nt) {
      bf16x8 bu = *(const bf16x8*)(dw1t + (long)(nt * 16 + cl) * 128 + s * 32 + kh * 8);
      uu[0][nt] = __builtin_amdgcn_mfma_f32_16x16x32_bf16(az0, bu, uu[0][nt], 0, 0, 0);
      uu[1][nt] = __builtin_amdgcn_mfma_f32_16x16x32_bf16(az1, bu, uu[1][nt], 0, 0, 0);
    }
  }
#pragma unroll
  for (int t = 0; t < 2; ++t)
#pragma unroll
    for (int nt = 0; nt < 8; ++nt) {
      float bb = db1[nt * 16 + cl];
#pragma unroll
      for (int i = 0; i < 4; ++i) {
        int r = wrow0 + t * 16 + kh * 4 + i;
        if (r < N_NODES) u16[(long)r * 128 + nt * 16 + cl] = f2bf(uu[t][nt][i] + bb);
      }
    }

  // ---- pass v (reuse uu registers) ----
#pragma unroll
  for (int t = 0; t < 2; ++t)
#pragma unroll
    for (int nt = 0; nt < 8; ++nt) uu[t][nt] = (f32x4){0.f, 0.f, 0.f, 0.f};
#pragma unroll
  for (int s = 0; s < 4; ++s) {
    const int zr0 = cl;
    const int zr1 = 16 + cl;
    bf16x8 az0 = *(const bf16x8*)(zb + ((zr0 * 256 + s * 64 + kh * 16) ^ ((zr0 & 7) << 4)));
    bf16x8 az1 = *(const bf16x8*)(zb + ((zr1 * 256 + s * 64 + kh * 16) ^ ((zr1 & 7) << 4)));
#pragma unroll
    for (int nt = 0; nt < 8; ++nt) {
      bf16x8 bv = *(const bf16x8*)(dw1t + (long)((nt + 8) * 16 + cl) * 128 + s * 32 + kh * 8);
      uu[0][nt] = __builtin_amdgcn_mfma_f32_16x16x32_bf16(az0, bv, uu[0][nt], 0, 0, 0);
      uu[1][nt] = __builtin_amdgcn_mfma_f32_16x16x32_bf16(az1, bv, uu[1][nt], 0, 0, 0);
    }
  }
#pragma unroll
  for (int t = 0; t < 2; ++t)
#pragma unroll
    for (int nt = 0; nt < 8; ++nt)
#pragma unroll
      for (int i = 0; i < 4; ++i) {
        int r = wrow0 + t * 16 + kh * 4 + i;
        if (r < N_NODES) v16[(long)r * 128 + nt * 16 + cl] = f2bf(uu[t][nt][i]);
      }
}

// ---------------- per-label-edge decoder: bucketed, 16 lanes/edge ----------------
__global__ __launch_bounds__(256) void k_edge2(
    const int* __restrict__ lblcnt, const int2* __restrict__ lbin,
    const unsigned short* __restrict__ u16, const unsigned short* __restrict__ v16,
    const float* __restrict__ dw2, const float* __restrict__ db2,
    float* __restrict__ out) {
  const int lane = threadIdx.x & 63;
  const int wv = threadIdx.x >> 6;  // 0..3
  const int g = lane >> 4;          // edge slot within wave: 0..3
  const int q = lane & 15;
  const int b = blockIdx.x / (LCAP / 16);          // bucket
  const int chunk = blockIdx.x % (LCAP / 16);      // chunks of 16 slots
  const int idx = chunk * 16 + wv * 4 + g;
  if (idx >= lblcnt[b]) return;
  int2 rec = lbin[(long)b * LCAP + idx];
  int d = rec.x;
  int s = (b << 9) + (rec.y & 511);
  int e = rec.y >> 9;

  bf16x8 uu = *(const bf16x8*)(u16 + (long)s * 128 + q * 8);
  bf16x8 vv = *(const bf16x8*)(v16 + (long)d * 128 + q * 8);
  float4 w0 = *(const float4*)&dw2[q * 8];
  float4 w1 = *(const float4*)&dw2[q * 8 + 4];
  float w8[8] = {w0.x, w0.y, w0.z, w0.w, w1.x, w1.y, w1.z, w1.w};
  float sum = 0.0f;
#pragma unroll
  for (int i = 0; i < 8; ++i) {
    float h = fmaxf(bfs(uu[i]) + bfs(vv[i]), 0.0f);
    sum = fmaf(h, w8[i], sum);
  }
  sum += __shfl_xor(sum, 1);
  sum += __shfl_xor(sum, 2);
  sum += __shfl_xor(sum, 4);
  sum += __shfl_xor(sum, 8);
  if (q == 0) out[e] = sum + db2[0];
}

extern "C" void kernel_launch(void* const* d_in, const int* in_sizes, int n_in,
                              void* d_out, int out_size, void* d_ws, size_t ws_size,
                              hipStream_t stream) {
  const float* x   = (const float*)d_in[0];
  const int*   ei  = (const int*)d_in[1];
  const int*   eli = (const int*)d_in[2];
  const float* w1l = (const float*)d_in[3];
  const float* b1l = (const float*)d_in[4];
  const float* w1r = (const float*)d_in[5];
  const float* w2l = (const float*)d_in[6];
  const float* b2l = (const float*)d_in[7];
  const float* w2r = (const float*)d_in[8];
  const float* dw1 = (const float*)d_in[9];
  const float* db1 = (const float*)d_in[10];
  const float* dw2 = (const float*)d_in[11];
  const float* db2 = (const float*)d_in[12];
  float* out = (float*)d_out;

  // ---- workspace layout (byte offsets, 16B aligned) ----
  char* wsb = (char*)d_ws;
  float* inv     = (float*)(wsb + 0);              // 400000
  int*   deg_i   = (int*)(wsb + 400000);           // 400000
  int*   rowptr  = (int*)(wsb + 800000);           // 400032
  int*   gcursor = (int*)(wsb + 1200032);          // 1024
  int*   csr     = (int*)(wsb + 1201056);          // 6400000
  int*   binned  = (int*)(wsb + 7601056);          // 6400000
  unsigned short* x16  = (unsigned short*)(wsb + 14001056);   // 12.8 MB
  unsigned short* m1   = (unsigned short*)(wsb + 26801056);   // 12.8 MB
  unsigned short* u16  = (unsigned short*)(wsb + 14001056);   // 25.6 MB (aliases x16+m1)
  unsigned short* h16  = (unsigned short*)(wsb + 39601056);   // 25.6 MB
  unsigned short* m2   = (unsigned short*)(wsb + 65201056);   // 25.6 MB
  unsigned short* v16  = (unsigned short*)(wsb + 90801056);   // 25.6 MB
  unsigned short* w1lt = (unsigned short*)(wsb + 116401056);  // 16384
  unsigned short* w1rt = (unsigned short*)(wsb + 116417440);  // 16384
  unsigned short* w2lt = (unsigned short*)(wsb + 116433824);  // 32768
  unsigned short* w2rt = (unsigned short*)(wsb + 116466592);  // 32768
  unsigned short* dw1t = (unsigned short*)(wsb + 116499360);  // 65536
  int*   bsum    = (int*)(wsb + 116564896);        // 512
  int*   lblcnt  = (int*)(wsb + 116565408);        // 800 (196 used, pad)
  int2*  lbin    = (int2*)(wsb + 116566208);       // 196*3072*8 = 4816896 -> ends ~121.4 MB

  const int* srcp = ei;
  const int* dstp = ei + N_EDGES;
  const int* lsp  = eli;
  const int* ldp  = eli + N_LBL;

  // ---- CSR build + label-edge binning + prep ----
  hipMemsetAsync(deg_i, 0, N_NODES * sizeof(int), stream);
  hipMemsetAsync(lblcnt, 0, NBUCK * sizeof(int), stream);
  k_deg<<<N_EDGES / 256, 256, 0, stream>>>(dstp, deg_i);
  k_scan_a<<<NSCANB, 1024, 0, stream>>>(deg_i, rowptr, inv, bsum);
  k_scan_b<<<1, 128, 0, stream>>>(bsum, rowptr);
  k_scan_c<<<NSCANB, 1024, 0, stream>>>(rowptr, bsum, gcursor);
  k_bin<<<(N_EDGES + 4095) / 4096, 256, 0, stream>>>(srcp, dstp, gcursor, binned);
  k_fill2<<<NBUCK, 256, 0, stream>>>(rowptr, binned, csr);
  k_lbl_bin<<<(N_LBL + 4095) / 4096, 256, 0, stream>>>(lsp, ldp, lblcnt, lbin);
  k_prep<<<(1681920 + 255) / 256, 256, 0, stream>>>(
      x, w1l, w1r, w2l, w2r, dw1, x16, w1lt, w1rt, w2lt, w2rt, dw1t);

  // ---- layer 1 (MFMA) ----
  k_agg64<<<N_NODES / 4, 256, 0, stream>>>(rowptr, csr, x16, inv, m1);
  k_l1<<<(N_NODES + 127) / 128, 256, 0, stream>>>(m1, x16, w1lt, w1rt, b1l, h16);

  // ---- layer 2 + u/v (MFMA, barrier-free) ----
  k_agg128<<<N_NODES / 4, 256, 0, stream>>>(rowptr, csr, h16, inv, m2);
  k_l2uv<<<(N_NODES + 63) / 64, 128, 0, stream>>>(m2, h16, w2lt, w2rt, b2l, dw1t, db1, u16, v16);

  // ---- decoder edge MLP (bucketed) ----
  k_edge2<<<NBUCK * (LCAP / 16), 256, 0, stream>>>(lblcnt, lbin, u16, v16, dw2, db2, out);
}